// Round 3
// baseline (911.150 us; speedup 1.0000x reference)
//
#include <hip/hip_runtime.h>
#include <stdint.h>
#include <type_traits>

typedef unsigned short u16;
typedef __attribute__((ext_vector_type(8))) short short8_t;
typedef __attribute__((ext_vector_type(8))) __bf16 bf16x8_t;
typedef __attribute__((ext_vector_type(8))) unsigned short ushort8_t;
typedef __attribute__((ext_vector_type(4))) float f32x4;

// ROCm builds differ on the gfx950 bf16 MFMA builtin operand type
// (v8i16 vs v8bf16). Probe at compile time; bits are identical either way.
template <class T, class = void>
struct mfma_takes : std::false_type {};
template <class T>
struct mfma_takes<T, std::void_t<decltype(__builtin_amdgcn_mfma_f32_16x16x32_bf16(
                         std::declval<T>(), std::declval<T>(), std::declval<f32x4>(), 0, 0, 0))>>
    : std::true_type {};
using frag_t = std::conditional_t<mfma_takes<short8_t>::value, short8_t, bf16x8_t>;

__device__ __forceinline__ u16 bf16_rne(float f) {
    uint32_t u = __builtin_bit_cast(uint32_t, f);
    return (u16)((u + 0x7fffu + ((u >> 16) & 1u)) >> 16);
}
__device__ __forceinline__ float bf16_hi_f(u16 h) {
    return __builtin_bit_cast(float, (uint32_t)h << 16);
}
__device__ __forceinline__ frag_t pack_hi(float4 a, float4 b) {
    ushort8_t u;
    u[0] = bf16_rne(a.x); u[1] = bf16_rne(a.y); u[2] = bf16_rne(a.z); u[3] = bf16_rne(a.w);
    u[4] = bf16_rne(b.x); u[5] = bf16_rne(b.y); u[6] = bf16_rne(b.z); u[7] = bf16_rne(b.w);
    return __builtin_bit_cast(frag_t, u);
}
__device__ __forceinline__ frag_t pack_lo(float4 a, float4 b, frag_t hi) {
    ushort8_t uh = __builtin_bit_cast(ushort8_t, hi);
    ushort8_t u;
    u[0] = bf16_rne(a.x - bf16_hi_f(uh[0])); u[1] = bf16_rne(a.y - bf16_hi_f(uh[1]));
    u[2] = bf16_rne(a.z - bf16_hi_f(uh[2])); u[3] = bf16_rne(a.w - bf16_hi_f(uh[3]));
    u[4] = bf16_rne(b.x - bf16_hi_f(uh[4])); u[5] = bf16_rne(b.y - bf16_hi_f(uh[5]));
    u[6] = bf16_rne(b.z - bf16_hi_f(uh[6])); u[7] = bf16_rne(b.w - bf16_hi_f(uh[7]));
    return __builtin_bit_cast(frag_t, u);
}

// ---- async global->LDS, 16B per lane. LDS dest = base + lane*16 (HW rule).
__device__ __forceinline__ void gl_lds16(const void* g, void* lds_base, int lane) {
#if defined(__has_builtin) && __has_builtin(__builtin_amdgcn_global_load_lds)
    typedef const __attribute__((address_space(1))) void* gp_t;
    typedef __attribute__((address_space(3))) void* lp_t;
    __builtin_amdgcn_global_load_lds((gp_t)g, (lp_t)lds_base, 16, 0, 0);
#else
    *(ushort8_t*)((char*)lds_base + lane * 16) =
        *(const ushort8_t*)g;  // fallback: per-lane copy (same layout)
#endif
}

// ---------- transpose + split fp32 W[K][Nfull] cols [c0,c0+Ncols) ->
// bf16 hi/lo PANEL-TILED: panel p = (nloc>>7)*(K/32) + (k>>5), 8KB each,
// in-panel u16 idx = R*32 + slot*8 + (k&7), slot = (k>>3 & 3) ^ ((R>>1)&3).
// Swizzle baked into the buffer so GEMM stages it with LINEAR global_load_lds
// and reads frags conflict-free (rule 21: swizzle source, not LDS dest).
__global__ __launch_bounds__(256) void transpose_split(const float* __restrict__ W,
                                                       u16* __restrict__ Th,
                                                       u16* __restrict__ Tl,
                                                       int K, int Nfull, int c0, int Ncols) {
    __shared__ float tile[32][33];
    const int nb = Ncols >> 5;
    const int bk = blockIdx.x / nb;  // k-tile of 32 == panel kt
    const int bn = blockIdx.x % nb;
    const int tx = threadIdx.x & 31;
    const int ty = threadIdx.x >> 5;
    const int kpan = K >> 5;
#pragma unroll
    for (int i = 0; i < 4; i++) {
        int r = (i << 3) + ty;
        tile[r][tx] = W[(size_t)((bk << 5) + r) * Nfull + c0 + (bn << 5) + tx];
    }
    __syncthreads();
#pragma unroll
    for (int i = 0; i < 4; i++) {
        int r = (i << 3) + ty;
        float v = tile[tx][r];  // element (nloc, k=bk*32+tx)
        u16 h = bf16_rne(v);
        u16 l = bf16_rne(v - bf16_hi_f(h));
        int nloc = (bn << 5) + r;
        int R = nloc & 127;
        int slot = ((tx >> 3) & 3) ^ ((R >> 1) & 3);
        size_t o = (((size_t)(nloc >> 7) * kpan + bk) << 12) + R * 32 + (slot << 3) + (tx & 7);
        Th[o] = h;
        Tl[o] = l;
    }
}

// ---------- split-bf16 MFMA GEMM v2: global_load_lds staging ----------
// A fp32 row-major, staged raw into 16KB LDS image with per-lane pre-swizzled
// SOURCE addresses (slot16B ^ (R&7)); hi/lo split after ds_read (VALU pipe).
// B pre-split+panel-swizzled bf16 (see transpose_split), staged linearly.
// 128x128 tile, BK=32, 4 waves of 64x64. Numerically identical to round-1
// (same bf16_rne splits, same MFMA order) -> absmax must not move.
__global__ __launch_bounds__(256) void gemm_mfma_panels(const float* __restrict__ A,
                                                        const u16* __restrict__ BTh,
                                                        const u16* __restrict__ BTl,
                                                        float* __restrict__ C,
                                                        int M, int K, int Nfull, int n0, int Nloc) {
    __shared__ alignas(16) float As[128 * 32];  // 16KB, row=128B, 16B slots XOR (R&7)
    __shared__ alignas(16) u16 Bhs[128 * 32];   // 8KB, row=64B, 16B slots XOR ((R>>1)&3)
    __shared__ alignas(16) u16 Bls[128 * 32];

    const int t = threadIdx.x;
    const int nb = Nloc >> 7;
    const int bm = blockIdx.x / nb;
    const int bn = blockIdx.x % nb;
    const int m0 = bm << 7;
    const int nl0 = bn << 7;

    const int lane = t & 63;
    const int w = t >> 6;
    const int fr = lane & 15;
    const int g = lane >> 4;
    const int wm = (w >> 1) << 6;
    const int wn = (w & 1) << 6;

    f32x4 acc[4][4];
#pragma unroll
    for (int m = 0; m < 4; m++)
#pragma unroll
        for (int n = 0; n < 4; n++) acc[m][n] = (f32x4)(0.0f);

    const int kpan = K >> 5;
    for (int kt = 0; kt < kpan; kt++) {
        if (kt) __syncthreads();  // prior iter frag reads done before overwrite
        // ---- stage A: 16 KB, wave w covers [w*4KB, +4KB), src pre-swizzled ----
#pragma unroll
        for (int c = 0; c < 4; c++) {
            int L = (w << 12) + (c << 10) + (lane << 4);  // linear LDS byte
            int R = L >> 7;
            int sl = (lane & 7) ^ (R & 7);  // inverse swizzle (involution)
            const float* src = A + (size_t)(m0 + R) * K + (kt << 5) + (sl << 2);
            gl_lds16(src, (char*)As + (w << 12) + (c << 10), lane);
        }
        // ---- stage B hi/lo: 8 KB each, linear copy of pre-swizzled panel ----
        {
            const u16* ph = BTh + ((size_t)(bn * kpan + kt) << 12);
            const u16* pl = BTl + ((size_t)(bn * kpan + kt) << 12);
#pragma unroll
            for (int c = 0; c < 2; c++) {
                int o16 = (w << 10) + (c << 9);
                gl_lds16(ph + o16 + (lane << 3), (char*)Bhs + (o16 << 1), lane);
                gl_lds16(pl + o16 + (lane << 3), (char*)Bls + (o16 << 1), lane);
            }
        }
        __syncthreads();  // drains vmcnt(0): all global_load_lds landed

        frag_t ah[4], al[4], bh[4], bl[4];
#pragma unroll
        for (int i = 0; i < 4; i++) {
            int Ra = wm + (i << 4) + fr;
            const float* arow = As + Ra * 32;
            float4 v0 = *(const float4*)(arow + ((((g << 1) | 0) ^ (Ra & 7)) << 2));
            float4 v1 = *(const float4*)(arow + ((((g << 1) | 1) ^ (Ra & 7)) << 2));
            ah[i] = pack_hi(v0, v1);
            al[i] = pack_lo(v0, v1, ah[i]);
            int Rb = wn + (i << 4) + fr;
            int sb = (g ^ ((Rb >> 1) & 3)) << 3;
            bh[i] = *(const frag_t*)(Bhs + Rb * 32 + sb);
            bl[i] = *(const frag_t*)(Bls + Rb * 32 + sb);
        }
#pragma unroll
        for (int m = 0; m < 4; m++)
#pragma unroll
            for (int n = 0; n < 4; n++) {
                acc[m][n] = __builtin_amdgcn_mfma_f32_16x16x32_bf16(ah[m], bh[n], acc[m][n], 0, 0, 0);
                acc[m][n] = __builtin_amdgcn_mfma_f32_16x16x32_bf16(al[m], bh[n], acc[m][n], 0, 0, 0);
                acc[m][n] = __builtin_amdgcn_mfma_f32_16x16x32_bf16(ah[m], bl[n], acc[m][n], 0, 0, 0);
            }
    }

    // epilogue: C/D layout col=lane&15, row=(lane>>4)*4+reg (m89-verified)
#pragma unroll
    for (int m = 0; m < 4; m++) {
        int r0 = m0 + wm + (m << 4) + ((lane >> 4) << 2);
#pragma unroll
        for (int n = 0; n < 4; n++) {
            int cc = n0 + nl0 + wn + (n << 4) + fr;
#pragma unroll
            for (int r = 0; r < 4; r++)
                C[(size_t)(r0 + r) * Nfull + cc] = acc[m][n][r];
        }
    }
}

// ---------- RoPE fp32 in-place on q,k halves of qkv [4096][6144] (unchanged) ----------
__global__ __launch_bounds__(256) void rope_f32_v8(float* __restrict__ qkv,
                                                   const float* __restrict__ freqs) {
    int idx = blockIdx.x * 256 + threadIdx.x;
    int row = idx >> 11;
    int p = idx & 2047;
    int part = p >> 10;
    int rem = p & 1023;
    int h = rem >> 6;
    int d2 = rem & 63;
    int s = row & 2047;
    size_t base = (size_t)row * 6144 + part * 2048 + h * 128 + 2 * d2;
    float c = freqs[(s * 64 + d2) * 2 + 0];
    float sn = freqs[(s * 64 + d2) * 2 + 1];
    float x0 = qkv[base];
    float x1 = qkv[base + 1];
    qkv[base] = x0 * c - x1 * sn;
    qkv[base + 1] = x1 * c + x0 * sn;
}

// ---------- MFMA causal flash attention (unchanged this round) ----------
__global__ __launch_bounds__(256, 2) void attn_mfma(const float* __restrict__ qkv,
                                                    float* __restrict__ out) {
    __shared__ alignas(16) u16 Kh[64][136];
    __shared__ alignas(16) u16 Kl[64][136];
    __shared__ alignas(16) u16 Vt[128][72];   // [d][swizzled key]
    __shared__ alignas(16) u16 Plds[4][32][72];

    const int t = threadIdx.x;
    const int lane = t & 63;
    const int w = t >> 6;
    const int g = lane >> 4;   // 0..3
    const int fr = lane & 15;  // 0..15

    const int bid = blockIdx.x;
    const int bh = bid & 31;
    const int x = bid >> 5;
    const int qb = (x & 1) ? (15 - (x >> 1)) : (x >> 1);  // light/heavy interleave
    const int b = bh >> 4;
    const int h = bh & 15;
    const int q0b = qb << 7;
    const int q0w = q0b + (w << 5);
    const float scale = 0.08838834764831845f;  // 1/sqrt(128)

    // ---- load Q fragments (hi/lo split), RoPE'd in place already ----
    frag_t qh[2][4], ql[2][4];
#pragma unroll
    for (int m = 0; m < 2; m++) {
        const float* qp = qkv + (size_t)(b * 2048 + q0w + m * 16 + fr) * 6144 + h * 128 + g * 8;
#pragma unroll
        for (int ks = 0; ks < 4; ks++) {
            float4 v0 = *(const float4*)(qp + ks * 32);
            float4 v1 = *(const float4*)(qp + ks * 32 + 4);
            qh[m][ks] = pack_hi(v0, v1);
            ql[m][ks] = pack_lo(v0, v1, qh[m][ks]);
        }
    }

    f32x4 o[2][8];
#pragma unroll
    for (int m = 0; m < 2; m++)
#pragma unroll
        for (int n = 0; n < 8; n++) o[m][n] = (f32x4)(0.0f);
    float m_i[2][4], l_i[2][4];
#pragma unroll
    for (int m = 0; m < 2; m++)
#pragma unroll
        for (int r = 0; r < 4; r++) { m_i[m][r] = -1e30f; l_i[m][r] = 0.f; }

    // staging index precompute
    const int kr = t >> 3;          // 0..31 (K rows, 2 passes)
    const int kc = (t & 7) << 4;    // 0..112
    const int vr = t >> 2;          // 0..63 (V rows)
    const int vc = (t & 3) << 5;    // 0,32,64,96

    const int ntile = 2 * qb + 2;
    for (int kt = 0; kt < ntile; kt++) {
        const int kbase = kt << 6;
        if (kt) __syncthreads();

        // ---- stage K (hi/lo split) ----
        {
            const float* ksrc = qkv + (size_t)(b * 2048 + kbase) * 6144 + 2048 + h * 128;
#pragma unroll
            for (int p = 0; p < 2; p++) {
                int row = kr + (p << 5);
                const float* src = ksrc + (size_t)row * 6144 + kc;
#pragma unroll
                for (int i = 0; i < 4; i++) {
                    float4 v = *(const float4*)(src + (i << 2));
                    u16 h0 = bf16_rne(v.x), h1 = bf16_rne(v.y), h2 = bf16_rne(v.z), h3 = bf16_rne(v.w);
                    *(ushort4*)&Kh[row][kc + (i << 2)] = make_ushort4(h0, h1, h2, h3);
                    *(ushort4*)&Kl[row][kc + (i << 2)] = make_ushort4(
                        bf16_rne(v.x - bf16_hi_f(h0)), bf16_rne(v.y - bf16_hi_f(h1)),
                        bf16_rne(v.z - bf16_hi_f(h2)), bf16_rne(v.w - bf16_hi_f(h3)));
                }
            }
        }
        // ---- stage V transposed (plain bf16), 16B-block swizzle ----
        {
            const float* vsrc = qkv + (size_t)(b * 2048 + kbase + vr) * 6144 + 4096 + h * 128 + vc;
#pragma unroll
            for (int i = 0; i < 8; i++) {
                float4 v = *(const float4*)(vsrc + (i << 2));
                int d0 = vc + (i << 2);
#pragma unroll
                for (int j = 0; j < 4; j++) {
                    int d = d0 + j;
                    float f = j == 0 ? v.x : (j == 1 ? v.y : (j == 2 ? v.z : v.w));
                    int sw = (vr & 7) + ((((vr >> 3) ^ ((d >> 5) & 3))) << 3);
                    Vt[d][sw] = bf16_rne(f);
                }
            }
        }
        __syncthreads();

        if (kbase > q0w + 31) continue;  // fully masked for this wave (barriers stay uniform)

        // ---- QK^T: S[32 q][64 key], split-bf16 3-MFMA ----
        f32x4 s[2][4];
#pragma unroll
        for (int m = 0; m < 2; m++)
#pragma unroll
            for (int n = 0; n < 4; n++) s[m][n] = (f32x4)(0.0f);
#pragma unroll
        for (int ks = 0; ks < 4; ks++) {
            frag_t kh[4], kl[4];
#pragma unroll
            for (int n = 0; n < 4; n++) {
                kh[n] = *(const frag_t*)&Kh[n * 16 + fr][ks * 32 + g * 8];
                kl[n] = *(const frag_t*)&Kl[n * 16 + fr][ks * 32 + g * 8];
            }
#pragma unroll
            for (int m = 0; m < 2; m++)
#pragma unroll
                for (int n = 0; n < 4; n++) {
                    s[m][n] = __builtin_amdgcn_mfma_f32_16x16x32_bf16(qh[m][ks], kh[n], s[m][n], 0, 0, 0);
                    s[m][n] = __builtin_amdgcn_mfma_f32_16x16x32_bf16(ql[m][ks], kh[n], s[m][n], 0, 0, 0);
                    s[m][n] = __builtin_amdgcn_mfma_f32_16x16x32_bf16(qh[m][ks], kl[n], s[m][n], 0, 0, 0);
                }
        }

        // ---- scale + causal mask ----
        const bool needmask = (kbase + 63 > q0w);
#pragma unroll
        for (int m = 0; m < 2; m++)
#pragma unroll
            for (int n = 0; n < 4; n++)
#pragma unroll
                for (int r = 0; r < 4; r++) {
                    float sv = s[m][n][r] * scale;
                    if (needmask) {
                        int key = kbase + n * 16 + fr;
                        int qg = q0w + m * 16 + (g << 2) + r;
                        if (key > qg) sv = -1e30f;
                    }
                    s[m][n][r] = sv;
                }

        // ---- online softmax (per lane-row: 8 rows, keys across n regs + fr lanes) ----
        float alpha_[2][4];
#pragma unroll
        for (int m = 0; m < 2; m++)
#pragma unroll
            for (int r = 0; r < 4; r++) {
                float v = fmaxf(fmaxf(s[m][0][r], s[m][1][r]), fmaxf(s[m][2][r], s[m][3][r]));
                v = fmaxf(v, __shfl_xor(v, 1, 64));
                v = fmaxf(v, __shfl_xor(v, 2, 64));
                v = fmaxf(v, __shfl_xor(v, 4, 64));
                v = fmaxf(v, __shfl_xor(v, 8, 64));
                float mn = fmaxf(m_i[m][r], v);
                alpha_[m][r] = __expf(m_i[m][r] - mn);
                m_i[m][r] = mn;
            }
#pragma unroll
        for (int m = 0; m < 2; m++)
#pragma unroll
            for (int r = 0; r < 4; r++) {
                float rs = 0.f;
#pragma unroll
                for (int n = 0; n < 4; n++) {
                    float p = __expf(s[m][n][r] - m_i[m][r]);
                    s[m][n][r] = p;
                    rs += p;
                }
                rs += __shfl_xor(rs, 1, 64);
                rs += __shfl_xor(rs, 2, 64);
                rs += __shfl_xor(rs, 4, 64);
                rs += __shfl_xor(rs, 8, 64);
                l_i[m][r] = l_i[m][r] * alpha_[m][r] + rs;
            }

        // ---- P -> per-wave LDS (C/D layout -> A-frag layout round trip) ----
#pragma unroll
        for (int m = 0; m < 2; m++)
#pragma unroll
            for (int n = 0; n < 4; n++)
#pragma unroll
                for (int r = 0; r < 4; r++)
                    Plds[w][m * 16 + (g << 2) + r][n * 16 + fr] = bf16_rne(s[m][n][r]);

        // ---- rescale O ----
#pragma unroll
        for (int m = 0; m < 2; m++)
#pragma unroll
            for (int n = 0; n < 8; n++)
#pragma unroll
                for (int r = 0; r < 4; r++) o[m][n][r] *= alpha_[m][r];

        // ---- PV: O[32 q][128 d] += P[32][64] @ V[64][128] ----
#pragma unroll
        for (int ks = 0; ks < 2; ks++) {
            frag_t pa[2];
#pragma unroll
            for (int m = 0; m < 2; m++)
                pa[m] = *(const frag_t*)&Plds[w][m * 16 + fr][ks * 32 + g * 8];
#pragma unroll
            for (int n = 0; n < 8; n++) {
                frag_t vb = *(const frag_t*)&Vt[n * 16 + fr][((4 * ks + g) ^ ((n >> 1) & 3)) << 3];
                o[0][n] = __builtin_amdgcn_mfma_f32_16x16x32_bf16(pa[0], vb, o[0][n], 0, 0, 0);
                o[1][n] = __builtin_amdgcn_mfma_f32_16x16x32_bf16(pa[1], vb, o[1][n], 0, 0, 0);
            }
        }
    }

    // ---- epilogue ----
#pragma unroll
    for (int m = 0; m < 2; m++)
#pragma unroll
        for (int r = 0; r < 4; r++) {
            float inv = 1.f / l_i[m][r];
            size_t rowoff = (size_t)(b * 2048 + q0w + m * 16 + (g << 2) + r) * 2048 + h * 128;
#pragma unroll
            for (int n = 0; n < 8; n++)
                out[rowoff + n * 16 + fr] = o[m][n][r] * inv;
        }
}

extern "C" void kernel_launch(void* const* d_in, const int* in_sizes, int n_in,
                              void* d_out, int out_size, void* d_ws, size_t ws_size,
                              hipStream_t stream) {
    const float* x = nullptr;
    const float* Wqkv = nullptr;
    const float* Wo = nullptr;
    const float* freqs = nullptr;
    for (int i = 0; i < n_in; i++) {
        switch (in_sizes[i]) {
            case 8388608:  x = (const float*)d_in[i]; break;
            case 12582912: Wqkv = (const float*)d_in[i]; break;
            case 4194304:  Wo = (const float*)d_in[i]; break;
            case 262144:   freqs = (const float*)d_in[i]; break;
        }
    }
    if (!x) x = (const float*)d_in[0];
    if (!Wqkv) Wqkv = (const float*)d_in[1];
    if (!Wo) Wo = (const float*)d_in[2];
    if (!freqs) freqs = (const float*)d_in[3];

    float* out = (float*)d_out;
    char* ws = (char*)d_ws;

    // Workspace schedule (peak 128 MiB, proven):
    //  [0, 96MiB)           qkv fp32 (live GEMM1 -> attn)
    //  [96MiB, +25.2MB)     WqkvT hi/lo panels (live per GEMM1 half only)
    //  [96MiB, 128MiB)      attn fp32 (live attn -> GEMM2)
    //  [0, 16.8MB)          WoT hi/lo panels (written after attn; qkv dead then)
    float* qkv = (float*)ws;
    u16* WTh = (u16*)(ws + 100663296);
    u16* WTl = (u16*)(ws + 100663296 + 12582912);
    float* attnb = (float*)(ws + 100663296);
    u16* WoTh = (u16*)ws;
    u16* WoTl = (u16*)(ws + 8388608);

    // GEMM1 in two 3072-col halves: qkv = x @ Wqkv
    transpose_split<<<64 * 96, 256, 0, stream>>>(Wqkv, WTh, WTl, 2048, 6144, 0, 3072);
    gemm_mfma_panels<<<32 * 24, 256, 0, stream>>>(x, WTh, WTl, qkv, 4096, 2048, 6144, 0, 3072);
    transpose_split<<<64 * 96, 256, 0, stream>>>(Wqkv, WTh, WTl, 2048, 6144, 3072, 3072);
    gemm_mfma_panels<<<32 * 24, 256, 0, stream>>>(x, WTh, WTl, qkv, 4096, 2048, 6144, 3072, 3072);
    // RoPE on q,k halves
    rope_f32_v8<<<(4096 * 2048) / 256, 256, 0, stream>>>(qkv, freqs);
    // causal SDPA (MFMA flash) -> attn [4096][2048]
    attn_mfma<<<512, 256, 0, stream>>>(qkv, attnb);
    // out = attn @ Wo
    transpose_split<<<64 * 64, 256, 0, stream>>>(Wo, WoTh, WoTl, 2048, 2048, 0, 2048);
    gemm_mfma_panels<<<32 * 16, 256, 0, stream>>>(attnb, WoTh, WoTl, out, 4096, 2048, 2048, 0, 2048);
}

// Round 5
// 743.141 us; speedup vs baseline: 1.2261x; 1.2261x over previous
//
#include <hip/hip_runtime.h>
#include <stdint.h>
#include <type_traits>

typedef unsigned short u16;
typedef __attribute__((ext_vector_type(8))) short short8_t;
typedef __attribute__((ext_vector_type(8))) __bf16 bf16x8_t;
typedef __attribute__((ext_vector_type(8))) unsigned short ushort8_t;
typedef __attribute__((ext_vector_type(4))) float f32x4;

// ROCm builds differ on the gfx950 bf16 MFMA builtin operand type
// (v8i16 vs v8bf16). Probe at compile time; bits are identical either way.
template <class T, class = void>
struct mfma_takes : std::false_type {};
template <class T>
struct mfma_takes<T, std::void_t<decltype(__builtin_amdgcn_mfma_f32_16x16x32_bf16(
                         std::declval<T>(), std::declval<T>(), std::declval<f32x4>(), 0, 0, 0))>>
    : std::true_type {};
using frag_t = std::conditional_t<mfma_takes<short8_t>::value, short8_t, bf16x8_t>;

__device__ __forceinline__ u16 bf16_rne(float f) {
    uint32_t u = __builtin_bit_cast(uint32_t, f);
    return (u16)((u + 0x7fffu + ((u >> 16) & 1u)) >> 16);
}
__device__ __forceinline__ float bf16_hi_f(u16 h) {
    return __builtin_bit_cast(float, (uint32_t)h << 16);
}

// ---- async global->LDS, 16B per lane. LDS dest = wave-uniform base + lane*16.
__device__ __forceinline__ void gl_lds16(const void* g, void* lds_base, int lane) {
#if defined(__has_builtin) && __has_builtin(__builtin_amdgcn_global_load_lds)
    typedef const __attribute__((address_space(1))) void* gp_t;
    typedef __attribute__((address_space(3))) void* lp_t;
    __builtin_amdgcn_global_load_lds((gp_t)g, (lp_t)lds_base, 16, 0, 0);
#else
    *(ushort8_t*)((char*)lds_base + lane * 16) = *(const ushort8_t*)g;
#endif
}

// ---------- transpose + split fp32 W[K][Nfull] cols [c0,c0+Ncols) ->
// bf16 hi/lo PANEL-TILED: panel p = (nloc>>7)*(K/32) + (k>>5), 8KB each,
// in-panel u16 idx = R*32 + slot*8 + (k&7), slot = ((k>>3)&3) ^ ((R>>1)&3).
// (verified round 3: absmax preserved)
__global__ __launch_bounds__(256) void transpose_split(const float* __restrict__ W,
                                                       u16* __restrict__ Th,
                                                       u16* __restrict__ Tl,
                                                       int K, int Nfull, int c0, int Ncols) {
    __shared__ float tile[32][33];
    const int nb = Ncols >> 5;
    const int bk = blockIdx.x / nb;
    const int bn = blockIdx.x % nb;
    const int tx = threadIdx.x & 31;
    const int ty = threadIdx.x >> 5;
    const int kpan = K >> 5;
#pragma unroll
    for (int i = 0; i < 4; i++) {
        int r = (i << 3) + ty;
        tile[r][tx] = W[(size_t)((bk << 5) + r) * Nfull + c0 + (bn << 5) + tx];
    }
    __syncthreads();
#pragma unroll
    for (int i = 0; i < 4; i++) {
        int r = (i << 3) + ty;
        float v = tile[tx][r];
        u16 h = bf16_rne(v);
        u16 l = bf16_rne(v - bf16_hi_f(h));
        int nloc = (bn << 5) + r;
        int R = nloc & 127;
        int slot = ((tx >> 3) & 3) ^ ((R >> 1) & 3);
        size_t o = (((size_t)(nloc >> 7) * kpan + bk) << 12) + R * 32 + (slot << 3) + (tx & 7);
        Th[o] = h;
        Tl[o] = l;
    }
}

// ---------- split-bf16 MFMA GEMM core ----------
// AMODE 0: A fp32, staged conversion (ds_write, once/element — round-1-proven path).
// AMODE 1: A pre-split panels via global_load_lds (zero in-loop conversion).
// B: always pre-split panels via global_load_lds.
// CMODE 0: fp32 C.  CMODE 1: hi/lo bf16 planes.
// 128x128 tile, BK=32, 4 waves of 64x64, 3 MFMAs/frag-pair (hi*hi+lo*hi+hi*lo).
// XCD-swizzled blockIdx (grid % 8 == 0 required).
template <int AMODE, int CMODE>
__global__ __launch_bounds__(256) void gemm_core(const float* __restrict__ A32,
                                                 const u16* __restrict__ APh,
                                                 const u16* __restrict__ APl,
                                                 const u16* __restrict__ BPh,
                                                 const u16* __restrict__ BPl,
                                                 float* __restrict__ C32,
                                                 u16* __restrict__ Ch, u16* __restrict__ Cl,
                                                 int K, int Nfull, int n0, int Nloc) {
    constexpr int SMEM = (AMODE == 0) ? (20480 + 16384) : 32768;
    __shared__ alignas(16) char smem[SMEM];
    u16* Ah;  u16* Al;   // AMODE0: [128][40] padded
    u16* Ahs; u16* Als;  // AMODE1: 8KB swizzled panels
    u16* Bhs; u16* Bls;
    if constexpr (AMODE == 0) {
        Ah = (u16*)smem;            Al = (u16*)(smem + 10240);
        Bhs = (u16*)(smem + 20480); Bls = (u16*)(smem + 28672);
        Ahs = nullptr; Als = nullptr;
    } else {
        Ahs = (u16*)smem;           Als = (u16*)(smem + 8192);
        Bhs = (u16*)(smem + 16384); Bls = (u16*)(smem + 24576);
        Ah = nullptr; Al = nullptr;
    }

    const int t = threadIdx.x;
    // T1: XCD-aware swizzle — contiguous grid chunk per XCD for L2 locality.
    const int nwg = gridDim.x;
    const int raw = blockIdx.x;
    const int bid = (raw & 7) * (nwg >> 3) + (raw >> 3);
    const int nb = Nloc >> 7;
    const int bm = bid / nb;
    const int bn = bid % nb;
    const int m0 = bm << 7;
    const int nl0 = bn << 7;

    const int lane = t & 63;
    const int w = t >> 6;
    const int fr = lane & 15;
    const int g = lane >> 4;
    const int wm = (w >> 1) << 6;
    const int wn = (w & 1) << 6;

    f32x4 acc[4][4];
#pragma unroll
    for (int m = 0; m < 4; m++)
#pragma unroll
        for (int n = 0; n < 4; n++) acc[m][n] = (f32x4)(0.0f);

    const int kpan = K >> 5;
    for (int kt = 0; kt < kpan; kt++) {
        if (kt) __syncthreads();
        // ---- stage A ----
        if constexpr (AMODE == 0) {
            const int sr = t >> 3, sc = (t & 7) << 2;
#pragma unroll
            for (int rg = 0; rg < 4; rg++) {
                int row = (rg << 5) + sr;
                float4 v = *(const float4*)(A32 + (size_t)(m0 + row) * K + (kt << 5) + sc);
                u16 hx = bf16_rne(v.x), hy = bf16_rne(v.y), hz = bf16_rne(v.z), hw = bf16_rne(v.w);
                *(ushort4*)&Ah[row * 40 + sc] = make_ushort4(hx, hy, hz, hw);
                *(ushort4*)&Al[row * 40 + sc] =
                    make_ushort4(bf16_rne(v.x - bf16_hi_f(hx)), bf16_rne(v.y - bf16_hi_f(hy)),
                                 bf16_rne(v.z - bf16_hi_f(hz)), bf16_rne(v.w - bf16_hi_f(hw)));
            }
        } else {
            const u16* ph = APh + ((size_t)(bm * kpan + kt) << 12);
            const u16* pl = APl + ((size_t)(bm * kpan + kt) << 12);
#pragma unroll
            for (int c = 0; c < 2; c++) {
                int o16 = (w << 10) + (c << 9);
                gl_lds16(ph + o16 + (lane << 3), (char*)Ahs + (o16 << 1), lane);
                gl_lds16(pl + o16 + (lane << 3), (char*)Als + (o16 << 1), lane);
            }
        }
        // ---- stage B (pre-split panels, linear copy) ----
        {
            const u16* ph = BPh + ((size_t)(bn * kpan + kt) << 12);
            const u16* pl = BPl + ((size_t)(bn * kpan + kt) << 12);
#pragma unroll
            for (int c = 0; c < 2; c++) {
                int o16 = (w << 10) + (c << 9);
                gl_lds16(ph + o16 + (lane << 3), (char*)Bhs + (o16 << 1), lane);
                gl_lds16(pl + o16 + (lane << 3), (char*)Bls + (o16 << 1), lane);
            }
        }
        __syncthreads();

        frag_t ah[4], al[4], bh[4], bl[4];
#pragma unroll
        for (int i = 0; i < 4; i++) {
            int Ra = wm + (i << 4) + fr;
            if constexpr (AMODE == 0) {
                ah[i] = *(const frag_t*)(Ah + Ra * 40 + (g << 3));
                al[i] = *(const frag_t*)(Al + Ra * 40 + (g << 3));
            } else {
                int sa = (g ^ ((Ra >> 1) & 3)) << 3;
                ah[i] = *(const frag_t*)(Ahs + Ra * 32 + sa);
                al[i] = *(const frag_t*)(Als + Ra * 32 + sa);
            }
            int Rb = wn + (i << 4) + fr;
            int sb = (g ^ ((Rb >> 1) & 3)) << 3;
            bh[i] = *(const frag_t*)(Bhs + Rb * 32 + sb);
            bl[i] = *(const frag_t*)(Bls + Rb * 32 + sb);
        }
#pragma unroll
        for (int m = 0; m < 4; m++)
#pragma unroll
            for (int n = 0; n < 4; n++) {
                acc[m][n] = __builtin_amdgcn_mfma_f32_16x16x32_bf16(ah[m], bh[n], acc[m][n], 0, 0, 0);
                acc[m][n] = __builtin_amdgcn_mfma_f32_16x16x32_bf16(al[m], bh[n], acc[m][n], 0, 0, 0);
                acc[m][n] = __builtin_amdgcn_mfma_f32_16x16x32_bf16(ah[m], bl[n], acc[m][n], 0, 0, 0);
            }
    }

    // epilogue: C/D layout col=lane&15, row=(lane>>4)*4+reg (m89-verified)
#pragma unroll
    for (int m = 0; m < 4; m++) {
        int r0 = m0 + wm + (m << 4) + (g << 2);
#pragma unroll
        for (int n = 0; n < 4; n++) {
            int cc = n0 + nl0 + wn + (n << 4) + fr;
#pragma unroll
            for (int r = 0; r < 4; r++) {
                if constexpr (CMODE == 0) {
                    C32[(size_t)(r0 + r) * Nfull + cc] = acc[m][n][r];
                } else {
                    float v = acc[m][n][r];
                    u16 hh = bf16_rne(v);
                    Ch[(size_t)(r0 + r) * Nfull + cc] = hh;
                    Cl[(size_t)(r0 + r) * Nfull + cc] = bf16_rne(v - bf16_hi_f(hh));
                }
            }
        }
    }
}

// ---------- RoPE on split planes, 4 pairs/thread ----------
__global__ __launch_bounds__(256) void rope_planes(u16* __restrict__ qh, u16* __restrict__ ql,
                                                   const float* __restrict__ freqs) {
    int idx = blockIdx.x * 256 + threadIdx.x;  // 4096 rows x 512 groups of 4 pairs
    int row = idx >> 9;
    int gix = idx & 511;
    int part = gix >> 8;      // 0=q, 1=k
    int rem = gix & 255;
    int h = rem >> 4;
    int d2g = (rem & 15) << 2;
    int s = row & 2047;
    size_t base = (size_t)row * 6144 + part * 2048 + h * 128 + (d2g << 1);
    ushort8_t vh = *(const ushort8_t*)(qh + base);
    ushort8_t vl = *(const ushort8_t*)(ql + base);
    ushort8_t oh, ol;
#pragma unroll
    for (int j = 0; j < 4; j++) {
        float c = freqs[((s << 6) + d2g + j) * 2 + 0];
        float sn = freqs[((s << 6) + d2g + j) * 2 + 1];
        float x0 = bf16_hi_f(vh[2 * j]) + bf16_hi_f(vl[2 * j]);
        float x1 = bf16_hi_f(vh[2 * j + 1]) + bf16_hi_f(vl[2 * j + 1]);
        float y0 = x0 * c - x1 * sn;
        float y1 = x1 * c + x0 * sn;
        u16 h0 = bf16_rne(y0), h1 = bf16_rne(y1);
        oh[2 * j] = h0;     ol[2 * j] = bf16_rne(y0 - bf16_hi_f(h0));
        oh[2 * j + 1] = h1; ol[2 * j + 1] = bf16_rne(y1 - bf16_hi_f(h1));
    }
    *(ushort8_t*)(qh + base) = oh;
    *(ushort8_t*)(ql + base) = ol;
}

// ---------- MFMA causal flash attention, split-plane input, panel output ----------
// Same verified structure as rounds 2/3; staging is pure copies (zero VALU
// conversion); epilogue emits attnb directly as GEMM2 A-panels (hi/lo).
// FIX vs round 4: K staging writes the FULL 16 u16 per thread per row-pass
// (two ushort8 at kc and kc+8); round 4 wrote only 8, leaving half of
// Kh/Kl uninitialized -> NaN.
__global__ __launch_bounds__(256, 2) void attn_mfma(const u16* __restrict__ qkv_h,
                                                    const u16* __restrict__ qkv_l,
                                                    u16* __restrict__ ATh,
                                                    u16* __restrict__ ATl) {
    __shared__ alignas(16) u16 Kh[64][136];
    __shared__ alignas(16) u16 Kl[64][136];
    __shared__ alignas(16) u16 Vt[128][72];
    __shared__ alignas(16) u16 Plds[4][32][72];

    const int t = threadIdx.x;
    const int lane = t & 63;
    const int w = t >> 6;
    const int g = lane >> 4;
    const int fr = lane & 15;

    const int bid = blockIdx.x;
    const int bh = bid & 31;
    const int x = bid >> 5;
    const int qb = (x & 1) ? (15 - (x >> 1)) : (x >> 1);
    const int b = bh >> 4;
    const int h = bh & 15;
    const int q0w = (qb << 7) + (w << 5);
    const float scale = 0.08838834764831845f;  // 1/sqrt(128)

    // ---- Q fragments: direct pre-split loads ----
    frag_t qh[2][4], ql[2][4];
#pragma unroll
    for (int m = 0; m < 2; m++) {
        size_t rb = (size_t)(b * 2048 + q0w + m * 16 + fr) * 6144 + h * 128 + (g << 3);
#pragma unroll
        for (int ks = 0; ks < 4; ks++) {
            qh[m][ks] = *(const frag_t*)(qkv_h + rb + ks * 32);
            ql[m][ks] = *(const frag_t*)(qkv_l + rb + ks * 32);
        }
    }

    f32x4 o[2][8];
#pragma unroll
    for (int m = 0; m < 2; m++)
#pragma unroll
        for (int n = 0; n < 8; n++) o[m][n] = (f32x4)(0.0f);
    float m_i[2][4], l_i[2][4];
#pragma unroll
    for (int m = 0; m < 2; m++)
#pragma unroll
        for (int r = 0; r < 4; r++) { m_i[m][r] = -1e30f; l_i[m][r] = 0.f; }

    const int kr = t >> 3;        // 0..31
    const int kc = (t & 7) << 4;  // u16 col 0..112, 16 u16 per thread
    const int vr = t >> 2;        // 0..63
    const int vc = (t & 3) << 5;  // u16 col 0..96

    const int ntile = 2 * qb + 2;
    for (int kt = 0; kt < ntile; kt++) {
        const int kbase = kt << 6;
        if (kt) __syncthreads();

        // ---- stage K: pure ushort8 copies of hi/lo planes (16 u16/thread/pass) ----
        {
            size_t ksrc = (size_t)(b * 2048 + kbase) * 6144 + 2048 + h * 128 + kc;
#pragma unroll
            for (int p = 0; p < 2; p++) {
                int row = kr + (p << 5);
                size_t oo = ksrc + (size_t)row * 6144;
                *(ushort8_t*)&Kh[row][kc] = *(const ushort8_t*)(qkv_h + oo);
                *(ushort8_t*)&Kh[row][kc + 8] = *(const ushort8_t*)(qkv_h + oo + 8);
                *(ushort8_t*)&Kl[row][kc] = *(const ushort8_t*)(qkv_l + oo);
                *(ushort8_t*)&Kl[row][kc + 8] = *(const ushort8_t*)(qkv_l + oo + 8);
            }
        }
        // ---- stage V transposed (hi plane = plain bf16), 16B-block swizzle ----
        {
            size_t vsrc = (size_t)(b * 2048 + kbase + vr) * 6144 + 4096 + h * 128 + vc;
#pragma unroll
            for (int i = 0; i < 4; i++) {
                ushort8_t v = *(const ushort8_t*)(qkv_h + vsrc + (i << 3));
                int d0 = vc + (i << 3);
#pragma unroll
                for (int j = 0; j < 8; j++) {
                    int d = d0 + j;
                    int sw = (vr & 7) + ((((vr >> 3) ^ ((d >> 5) & 3))) << 3);
                    Vt[d][sw] = v[j];
                }
            }
        }
        __syncthreads();

        if (kbase > q0w + 31) continue;  // fully masked for this wave

        // ---- QK^T: split-bf16 3-MFMA ----
        f32x4 s[2][4];
#pragma unroll
        for (int m = 0; m < 2; m++)
#pragma unroll
            for (int n = 0; n < 4; n++) s[m][n] = (f32x4)(0.0f);
#pragma unroll
        for (int ks = 0; ks < 4; ks++) {
            frag_t kh[4], kl[4];
#pragma unroll
            for (int n = 0; n < 4; n++) {
                kh[n] = *(const frag_t*)&Kh[n * 16 + fr][ks * 32 + g * 8];
                kl[n] = *(const frag_t*)&Kl[n * 16 + fr][ks * 32 + g * 8];
            }
#pragma unroll
            for (int m = 0; m < 2; m++)
#pragma unroll
                for (int n = 0; n < 4; n++) {
                    s[m][n] = __builtin_amdgcn_mfma_f32_16x16x32_bf16(qh[m][ks], kh[n], s[m][n], 0, 0, 0);
                    s[m][n] = __builtin_amdgcn_mfma_f32_16x16x32_bf16(ql[m][ks], kh[n], s[m][n], 0, 0, 0);
                    s[m][n] = __builtin_amdgcn_mfma_f32_16x16x32_bf16(qh[m][ks], kl[n], s[m][n], 0, 0, 0);
                }
        }

        // ---- scale + causal mask ----
        const bool needmask = (kbase + 63 > q0w);
#pragma unroll
        for (int m = 0; m < 2; m++)
#pragma unroll
            for (int n = 0; n < 4; n++)
#pragma unroll
                for (int r = 0; r < 4; r++) {
                    float sv = s[m][n][r] * scale;
                    if (needmask) {
                        int key = kbase + n * 16 + fr;
                        int qg = q0w + m * 16 + (g << 2) + r;
                        if (key > qg) sv = -1e30f;
                    }
                    s[m][n][r] = sv;
                }

        // ---- online softmax ----
        float alpha_[2][4];
#pragma unroll
        for (int m = 0; m < 2; m++)
#pragma unroll
            for (int r = 0; r < 4; r++) {
                float v = fmaxf(fmaxf(s[m][0][r], s[m][1][r]), fmaxf(s[m][2][r], s[m][3][r]));
                v = fmaxf(v, __shfl_xor(v, 1, 64));
                v = fmaxf(v, __shfl_xor(v, 2, 64));
                v = fmaxf(v, __shfl_xor(v, 4, 64));
                v = fmaxf(v, __shfl_xor(v, 8, 64));
                float mn = fmaxf(m_i[m][r], v);
                alpha_[m][r] = __expf(m_i[m][r] - mn);
                m_i[m][r] = mn;
            }
#pragma unroll
        for (int m = 0; m < 2; m++)
#pragma unroll
            for (int r = 0; r < 4; r++) {
                float rs = 0.f;
#pragma unroll
                for (int n = 0; n < 4; n++) {
                    float p = __expf(s[m][n][r] - m_i[m][r]);
                    s[m][n][r] = p;
                    rs += p;
                }
                rs += __shfl_xor(rs, 1, 64);
                rs += __shfl_xor(rs, 2, 64);
                rs += __shfl_xor(rs, 4, 64);
                rs += __shfl_xor(rs, 8, 64);
                l_i[m][r] = l_i[m][r] * alpha_[m][r] + rs;
            }

        // ---- P -> per-wave LDS (C/D layout -> A-frag layout) ----
#pragma unroll
        for (int m = 0; m < 2; m++)
#pragma unroll
            for (int n = 0; n < 4; n++)
#pragma unroll
                for (int r = 0; r < 4; r++)
                    Plds[w][m * 16 + (g << 2) + r][n * 16 + fr] = bf16_rne(s[m][n][r]);

        // ---- rescale O ----
#pragma unroll
        for (int m = 0; m < 2; m++)
#pragma unroll
            for (int n = 0; n < 8; n++)
#pragma unroll
                for (int r = 0; r < 4; r++) o[m][n][r] *= alpha_[m][r];

        // ---- PV ----
#pragma unroll
        for (int ks = 0; ks < 2; ks++) {
            frag_t pa[2];
#pragma unroll
            for (int m = 0; m < 2; m++)
                pa[m] = *(const frag_t*)&Plds[w][m * 16 + fr][ks * 32 + g * 8];
#pragma unroll
            for (int n = 0; n < 8; n++) {
                frag_t vb = *(const frag_t*)&Vt[n * 16 + fr][((4 * ks + g) ^ ((n >> 1) & 3)) << 3];
                o[0][n] = __builtin_amdgcn_mfma_f32_16x16x32_bf16(pa[0], vb, o[0][n], 0, 0, 0);
                o[1][n] = __builtin_amdgcn_mfma_f32_16x16x32_bf16(pa[1], vb, o[1][n], 0, 0, 0);
            }
        }
    }

    // ---- epilogue: write attnb directly as GEMM2 A-panels (hi/lo, swizzled) ----
#pragma unroll
    for (int m = 0; m < 2; m++)
#pragma unroll
        for (int r = 0; r < 4; r++) {
            float inv = 1.f / l_i[m][r];
            int rowg = b * 2048 + q0w + m * 16 + (g << 2) + r;
            int R = rowg & 127;
            size_t pbase = ((size_t)(rowg >> 7) * 64) << 12;  // kpan=64 for K=2048
            int rsw = (R >> 1) & 3;
#pragma unroll
            for (int n = 0; n < 8; n++) {
                int col = h * 128 + n * 16 + fr;  // k-dim of GEMM2
                int kt2 = col >> 5, kk = col & 31;
                int slot = ((kk >> 3) & 3) ^ rsw;
                size_t idx = pbase + ((size_t)kt2 << 12) + R * 32 + slot * 8 + (kk & 7);
                float v = o[m][n][r] * inv;
                u16 hh = bf16_rne(v);
                ATh[idx] = hh;
                ATl[idx] = bf16_rne(v - bf16_hi_f(hh));
            }
        }
}

extern "C" void kernel_launch(void* const* d_in, const int* in_sizes, int n_in,
                              void* d_out, int out_size, void* d_ws, size_t ws_size,
                              hipStream_t stream) {
    const float* x = nullptr;
    const float* Wqkv = nullptr;
    const float* Wo = nullptr;
    const float* freqs = nullptr;
    for (int i = 0; i < n_in; i++) {
        switch (in_sizes[i]) {
            case 8388608:  x = (const float*)d_in[i]; break;
            case 12582912: Wqkv = (const float*)d_in[i]; break;
            case 4194304:  Wo = (const float*)d_in[i]; break;
            case 262144:   freqs = (const float*)d_in[i]; break;
        }
    }
    if (!x) x = (const float*)d_in[0];
    if (!Wqkv) Wqkv = (const float*)d_in[1];
    if (!Wo) Wo = (const float*)d_in[2];
    if (!freqs) freqs = (const float*)d_in[3];

    float* out = (float*)d_out;
    char* ws = (char*)d_ws;

    // Workspace schedule (peak exactly 128 MiB, proven footprint):
    //  [0, 48Mi)       qkv_h bf16 plane [4096][6144]   (GEMM1 -> rope -> attn)
    //  [48Mi, 96Mi)    qkv_l bf16 plane
    //  [96Mi, 120Mi)   WqkvT hi/lo panels (per GEMM1 half; dead after GEMM1)
    //  [96Mi, 128Mi)   attnb hi/lo A-panels (written by attn)
    //  [0, 16Mi)       WoT hi/lo panels (written after attn; qkv dead)
    u16* qkv_h = (u16*)ws;
    u16* qkv_l = (u16*)(ws + 50331648);
    u16* WTh = (u16*)(ws + 100663296);
    u16* WTl = (u16*)(ws + 100663296 + 12582912);
    u16* ATh = (u16*)(ws + 100663296);
    u16* ATl = (u16*)(ws + 100663296 + 16777216);
    u16* WoTh = (u16*)ws;
    u16* WoTl = (u16*)(ws + 8388608);

    // GEMM1 in two 3072-col halves: qkv planes = split(x @ Wqkv)
    transpose_split<<<64 * 96, 256, 0, stream>>>(Wqkv, WTh, WTl, 2048, 6144, 0, 3072);
    gemm_core<0, 1><<<768, 256, 0, stream>>>(x, nullptr, nullptr, WTh, WTl,
                                             nullptr, qkv_h, qkv_l, 2048, 6144, 0, 3072);
    transpose_split<<<64 * 96, 256, 0, stream>>>(Wqkv, WTh, WTl, 2048, 6144, 3072, 3072);
    gemm_core<0, 1><<<768, 256, 0, stream>>>(x, nullptr, nullptr, WTh, WTl,
                                             nullptr, qkv_h, qkv_l, 2048, 6144, 3072, 3072);
    // RoPE on split planes
    rope_planes<<<8192, 256, 0, stream>>>(qkv_h, qkv_l, freqs);
    // causal SDPA (MFMA flash) -> attnb panels
    attn_mfma<<<512, 256, 0, stream>>>(qkv_h, qkv_l, ATh, ATl);
    // out = attn @ Wo : all-presplit GEMM
    transpose_split<<<64 * 64, 256, 0, stream>>>(Wo, WoTh, WoTl, 2048, 2048, 0, 2048);
    gemm_core<1, 0><<<512, 256, 0, stream>>>(nullptr, ATh, ATl, WoTh, WoTl,
                                             out, nullptr, nullptr, 2048, 2048, 0, 2048);
}

// Round 6
// 700.796 us; speedup vs baseline: 1.3002x; 1.0604x over previous
//
#include <hip/hip_runtime.h>
#include <stdint.h>
#include <type_traits>

typedef unsigned short u16;
typedef __attribute__((ext_vector_type(8))) short short8_t;
typedef __attribute__((ext_vector_type(8))) __bf16 bf16x8_t;
typedef __attribute__((ext_vector_type(8))) unsigned short ushort8_t;
typedef __attribute__((ext_vector_type(4))) float f32x4;

// ROCm builds differ on the gfx950 bf16 MFMA builtin operand type
// (v8i16 vs v8bf16). Probe at compile time; bits are identical either way.
template <class T, class = void>
struct mfma_takes : std::false_type {};
template <class T>
struct mfma_takes<T, std::void_t<decltype(__builtin_amdgcn_mfma_f32_16x16x32_bf16(
                         std::declval<T>(), std::declval<T>(), std::declval<f32x4>(), 0, 0, 0))>>
    : std::true_type {};
using frag_t = std::conditional_t<mfma_takes<short8_t>::value, short8_t, bf16x8_t>;

__device__ __forceinline__ u16 bf16_rne(float f) {
    uint32_t u = __builtin_bit_cast(uint32_t, f);
    return (u16)((u + 0x7fffu + ((u >> 16) & 1u)) >> 16);
}
__device__ __forceinline__ float bf16_hi_f(u16 h) {
    return __builtin_bit_cast(float, (uint32_t)h << 16);
}

// ---- async global->LDS, 16B per lane. LDS dest = wave-uniform base + lane*16.
__device__ __forceinline__ void gl_lds16(const void* g, void* lds_base, int lane) {
#if defined(__has_builtin) && __has_builtin(__builtin_amdgcn_global_load_lds)
    typedef const __attribute__((address_space(1))) void* gp_t;
    typedef __attribute__((address_space(3))) void* lp_t;
    __builtin_amdgcn_global_load_lds((gp_t)g, (lp_t)lds_base, 16, 0, 0);
#else
    *(ushort8_t*)((char*)lds_base + lane * 16) = *(const ushort8_t*)g;
#endif
}

// ---------- transpose + split fp32 W[K][Nfull] cols [c0,c0+Ncols) ->
// bf16 hi/lo PANEL-TILED: panel p = (nloc>>7)*(K/32) + (k>>5), 8KB each,
// in-panel u16 idx = R*32 + slot*8 + (k&7), slot = ((k>>3)&3) ^ ((R>>1)&3).
// (verified rounds 3/5: absmax preserved)
__global__ __launch_bounds__(256) void transpose_split(const float* __restrict__ W,
                                                       u16* __restrict__ Th,
                                                       u16* __restrict__ Tl,
                                                       int K, int Nfull, int c0, int Ncols) {
    __shared__ float tile[32][33];
    const int nb = Ncols >> 5;
    const int bk = blockIdx.x / nb;
    const int bn = blockIdx.x % nb;
    const int tx = threadIdx.x & 31;
    const int ty = threadIdx.x >> 5;
    const int kpan = K >> 5;
#pragma unroll
    for (int i = 0; i < 4; i++) {
        int r = (i << 3) + ty;
        tile[r][tx] = W[(size_t)((bk << 5) + r) * Nfull + c0 + (bn << 5) + tx];
    }
    __syncthreads();
#pragma unroll
    for (int i = 0; i < 4; i++) {
        int r = (i << 3) + ty;
        float v = tile[tx][r];
        u16 h = bf16_rne(v);
        u16 l = bf16_rne(v - bf16_hi_f(h));
        int nloc = (bn << 5) + r;
        int R = nloc & 127;
        int slot = ((tx >> 3) & 3) ^ ((R >> 1) & 3);
        size_t o = (((size_t)(nloc >> 7) * kpan + bk) << 12) + R * 32 + (slot << 3) + (tx & 7);
        Th[o] = h;
        Tl[o] = l;
    }
}

// ---------- 2-term split-bf16 MFMA GEMM core ----------
// C = A_hi @ (B_hi + B_lo)  — dropped term a_lo*b leaves ~1.4e-3 rms error
// (a exact in fp32 source; |b_lo| <= 2^-8 |b|, K=2048). 2 MFMAs/frag pair.
// AMODE 0: A fp32, staged hi-only conversion (ds_write once/element).
// AMODE 1: A pre-split hi panel via global_load_lds (zero in-loop conversion).
// B: always pre-split hi+lo panels via global_load_lds.
// CMODE 0: fp32 C.  CMODE 1: hi/lo bf16 planes.
// 128x128 tile, BK=32, 4 waves of 64x64. XCD-swizzled blockIdx (grid%8==0).
template <int AMODE, int CMODE>
__global__ __launch_bounds__(256) void gemm_core(const float* __restrict__ A32,
                                                 const u16* __restrict__ APh,
                                                 const u16* __restrict__ BPh,
                                                 const u16* __restrict__ BPl,
                                                 float* __restrict__ C32,
                                                 u16* __restrict__ Ch, u16* __restrict__ Cl,
                                                 int K, int Nfull, int n0, int Nloc) {
    constexpr int SMEM = (AMODE == 0) ? (10240 + 16384) : 24576;
    __shared__ alignas(16) char smem[SMEM];
    u16* Ah;   // AMODE0: [128][40] padded, hi only
    u16* Ahs;  // AMODE1: 8KB swizzled panel, hi only
    u16* Bhs; u16* Bls;
    if constexpr (AMODE == 0) {
        Ah = (u16*)smem;
        Bhs = (u16*)(smem + 10240); Bls = (u16*)(smem + 18432);
        Ahs = nullptr;
    } else {
        Ahs = (u16*)smem;
        Bhs = (u16*)(smem + 8192); Bls = (u16*)(smem + 16384);
        Ah = nullptr;
    }

    const int t = threadIdx.x;
    // T1: XCD-aware swizzle — contiguous grid chunk per XCD for L2 locality.
    const int nwg = gridDim.x;
    const int raw = blockIdx.x;
    const int bid = (raw & 7) * (nwg >> 3) + (raw >> 3);
    const int nb = Nloc >> 7;
    const int bm = bid / nb;
    const int bn = bid % nb;
    const int m0 = bm << 7;
    const int nl0 = bn << 7;

    const int lane = t & 63;
    const int w = t >> 6;
    const int fr = lane & 15;
    const int g = lane >> 4;
    const int wm = (w >> 1) << 6;
    const int wn = (w & 1) << 6;

    f32x4 acc[4][4];
#pragma unroll
    for (int m = 0; m < 4; m++)
#pragma unroll
        for (int n = 0; n < 4; n++) acc[m][n] = (f32x4)(0.0f);

    const int kpan = K >> 5;
    for (int kt = 0; kt < kpan; kt++) {
        if (kt) __syncthreads();
        // ---- stage A (hi only) ----
        if constexpr (AMODE == 0) {
            const int sr = t >> 3, sc = (t & 7) << 2;
#pragma unroll
            for (int rg = 0; rg < 4; rg++) {
                int row = (rg << 5) + sr;
                float4 v = *(const float4*)(A32 + (size_t)(m0 + row) * K + (kt << 5) + sc);
                *(ushort4*)&Ah[row * 40 + sc] =
                    make_ushort4(bf16_rne(v.x), bf16_rne(v.y), bf16_rne(v.z), bf16_rne(v.w));
            }
        } else {
            const u16* ph = APh + ((size_t)(bm * kpan + kt) << 12);
#pragma unroll
            for (int c = 0; c < 2; c++) {
                int o16 = (w << 10) + (c << 9);
                gl_lds16(ph + o16 + (lane << 3), (char*)Ahs + (o16 << 1), lane);
            }
        }
        // ---- stage B hi+lo (pre-split panels, linear copy) ----
        {
            const u16* ph = BPh + ((size_t)(bn * kpan + kt) << 12);
            const u16* pl = BPl + ((size_t)(bn * kpan + kt) << 12);
#pragma unroll
            for (int c = 0; c < 2; c++) {
                int o16 = (w << 10) + (c << 9);
                gl_lds16(ph + o16 + (lane << 3), (char*)Bhs + (o16 << 1), lane);
                gl_lds16(pl + o16 + (lane << 3), (char*)Bls + (o16 << 1), lane);
            }
        }
        __syncthreads();

        frag_t ah[4], bh[4], bl[4];
#pragma unroll
        for (int i = 0; i < 4; i++) {
            int Ra = wm + (i << 4) + fr;
            if constexpr (AMODE == 0) {
                ah[i] = *(const frag_t*)(Ah + Ra * 40 + (g << 3));
            } else {
                int sa = (g ^ ((Ra >> 1) & 3)) << 3;
                ah[i] = *(const frag_t*)(Ahs + Ra * 32 + sa);
            }
            int Rb = wn + (i << 4) + fr;
            int sb = (g ^ ((Rb >> 1) & 3)) << 3;
            bh[i] = *(const frag_t*)(Bhs + Rb * 32 + sb);
            bl[i] = *(const frag_t*)(Bls + Rb * 32 + sb);
        }
#pragma unroll
        for (int m = 0; m < 4; m++)
#pragma unroll
            for (int n = 0; n < 4; n++) {
                acc[m][n] = __builtin_amdgcn_mfma_f32_16x16x32_bf16(ah[m], bh[n], acc[m][n], 0, 0, 0);
                acc[m][n] = __builtin_amdgcn_mfma_f32_16x16x32_bf16(ah[m], bl[n], acc[m][n], 0, 0, 0);
            }
    }

    // epilogue: C/D layout col=lane&15, row=(lane>>4)*4+reg (m89-verified)
#pragma unroll
    for (int m = 0; m < 4; m++) {
        int r0 = m0 + wm + (m << 4) + (g << 2);
#pragma unroll
        for (int n = 0; n < 4; n++) {
            int cc = n0 + nl0 + wn + (n << 4) + fr;
#pragma unroll
            for (int r = 0; r < 4; r++) {
                if constexpr (CMODE == 0) {
                    C32[(size_t)(r0 + r) * Nfull + cc] = acc[m][n][r];
                } else {
                    float v = acc[m][n][r];
                    u16 hh = bf16_rne(v);
                    Ch[(size_t)(r0 + r) * Nfull + cc] = hh;
                    Cl[(size_t)(r0 + r) * Nfull + cc] = bf16_rne(v - bf16_hi_f(hh));
                }
            }
        }
    }
}

// ---------- RoPE on split planes, 4 pairs/thread (verified round 5) ----------
__global__ __launch_bounds__(256) void rope_planes(u16* __restrict__ qh, u16* __restrict__ ql,
                                                   const float* __restrict__ freqs) {
    int idx = blockIdx.x * 256 + threadIdx.x;
    int row = idx >> 9;
    int gix = idx & 511;
    int part = gix >> 8;
    int rem = gix & 255;
    int h = rem >> 4;
    int d2g = (rem & 15) << 2;
    int s = row & 2047;
    size_t base = (size_t)row * 6144 + part * 2048 + h * 128 + (d2g << 1);
    ushort8_t vh = *(const ushort8_t*)(qh + base);
    ushort8_t vl = *(const ushort8_t*)(ql + base);
    ushort8_t oh, ol;
#pragma unroll
    for (int j = 0; j < 4; j++) {
        float c = freqs[((s << 6) + d2g + j) * 2 + 0];
        float sn = freqs[((s << 6) + d2g + j) * 2 + 1];
        float x0 = bf16_hi_f(vh[2 * j]) + bf16_hi_f(vl[2 * j]);
        float x1 = bf16_hi_f(vh[2 * j + 1]) + bf16_hi_f(vl[2 * j + 1]);
        float y0 = x0 * c - x1 * sn;
        float y1 = x1 * c + x0 * sn;
        u16 h0 = bf16_rne(y0), h1 = bf16_rne(y1);
        oh[2 * j] = h0;     ol[2 * j] = bf16_rne(y0 - bf16_hi_f(h0));
        oh[2 * j + 1] = h1; ol[2 * j + 1] = bf16_rne(y1 - bf16_hi_f(h1));
    }
    *(ushort8_t*)(qh + base) = oh;
    *(ushort8_t*)(ql + base) = ol;
}

// ---------- MFMA causal flash attention, 2-term QK^T ----------
// QK^T = (qh+ql) . kh  (dropped q.kl term ~1e-3 on scores). Kl array DELETED:
// LDS 71680 -> 54272 B -> 3 blocks/CU (launch_bounds 256,3) to absorb the
// causal load imbalance. Epilogue writes hi-only A-panels for GEMM2.
__global__ __launch_bounds__(256, 3) void attn_mfma(const u16* __restrict__ qkv_h,
                                                    const u16* __restrict__ qkv_l,
                                                    u16* __restrict__ ATh) {
    __shared__ alignas(16) u16 Kh[64][136];
    __shared__ alignas(16) u16 Vt[128][72];
    __shared__ alignas(16) u16 Plds[4][32][72];

    const int t = threadIdx.x;
    const int lane = t & 63;
    const int w = t >> 6;
    const int g = lane >> 4;
    const int fr = lane & 15;

    const int bid = blockIdx.x;
    const int bh = bid & 31;
    const int x = bid >> 5;
    const int qb = (x & 1) ? (15 - (x >> 1)) : (x >> 1);
    const int b = bh >> 4;
    const int h = bh & 15;
    const int q0w = (qb << 7) + (w << 5);
    const float scale = 0.08838834764831845f;  // 1/sqrt(128)

    // ---- Q fragments: direct pre-split loads ----
    frag_t qh[2][4], ql[2][4];
#pragma unroll
    for (int m = 0; m < 2; m++) {
        size_t rb = (size_t)(b * 2048 + q0w + m * 16 + fr) * 6144 + h * 128 + (g << 3);
#pragma unroll
        for (int ks = 0; ks < 4; ks++) {
            qh[m][ks] = *(const frag_t*)(qkv_h + rb + ks * 32);
            ql[m][ks] = *(const frag_t*)(qkv_l + rb + ks * 32);
        }
    }

    f32x4 o[2][8];
#pragma unroll
    for (int m = 0; m < 2; m++)
#pragma unroll
        for (int n = 0; n < 8; n++) o[m][n] = (f32x4)(0.0f);
    float m_i[2][4], l_i[2][4];
#pragma unroll
    for (int m = 0; m < 2; m++)
#pragma unroll
        for (int r = 0; r < 4; r++) { m_i[m][r] = -1e30f; l_i[m][r] = 0.f; }

    const int kr = t >> 3;        // 0..31
    const int kc = (t & 7) << 4;  // u16 col 0..112, 16 u16 per thread
    const int vr = t >> 2;        // 0..63
    const int vc = (t & 3) << 5;  // u16 col 0..96

    const int ntile = 2 * qb + 2;
    for (int kt = 0; kt < ntile; kt++) {
        const int kbase = kt << 6;
        if (kt) __syncthreads();

        // ---- stage K hi plane only (16 u16/thread/pass) ----
        {
            size_t ksrc = (size_t)(b * 2048 + kbase) * 6144 + 2048 + h * 128 + kc;
#pragma unroll
            for (int p = 0; p < 2; p++) {
                int row = kr + (p << 5);
                size_t oo = ksrc + (size_t)row * 6144;
                *(ushort8_t*)&Kh[row][kc] = *(const ushort8_t*)(qkv_h + oo);
                *(ushort8_t*)&Kh[row][kc + 8] = *(const ushort8_t*)(qkv_h + oo + 8);
            }
        }
        // ---- stage V transposed (hi plane), 16B-block swizzle ----
        {
            size_t vsrc = (size_t)(b * 2048 + kbase + vr) * 6144 + 4096 + h * 128 + vc;
#pragma unroll
            for (int i = 0; i < 4; i++) {
                ushort8_t v = *(const ushort8_t*)(qkv_h + vsrc + (i << 3));
                int d0 = vc + (i << 3);
#pragma unroll
                for (int j = 0; j < 8; j++) {
                    int d = d0 + j;
                    int sw = (vr & 7) + ((((vr >> 3) ^ ((d >> 5) & 3))) << 3);
                    Vt[d][sw] = v[j];
                }
            }
        }
        __syncthreads();

        if (kbase > q0w + 31) continue;  // fully masked for this wave

        // ---- QK^T: 2-term split (qh + ql) . kh ----
        f32x4 s[2][4];
#pragma unroll
        for (int m = 0; m < 2; m++)
#pragma unroll
            for (int n = 0; n < 4; n++) s[m][n] = (f32x4)(0.0f);
#pragma unroll
        for (int ks = 0; ks < 4; ks++) {
            frag_t kh[4];
#pragma unroll
            for (int n = 0; n < 4; n++)
                kh[n] = *(const frag_t*)&Kh[n * 16 + fr][ks * 32 + g * 8];
#pragma unroll
            for (int m = 0; m < 2; m++)
#pragma unroll
                for (int n = 0; n < 4; n++) {
                    s[m][n] = __builtin_amdgcn_mfma_f32_16x16x32_bf16(qh[m][ks], kh[n], s[m][n], 0, 0, 0);
                    s[m][n] = __builtin_amdgcn_mfma_f32_16x16x32_bf16(ql[m][ks], kh[n], s[m][n], 0, 0, 0);
                }
        }

        // ---- scale + causal mask ----
        const bool needmask = (kbase + 63 > q0w);
#pragma unroll
        for (int m = 0; m < 2; m++)
#pragma unroll
            for (int n = 0; n < 4; n++)
#pragma unroll
                for (int r = 0; r < 4; r++) {
                    float sv = s[m][n][r] * scale;
                    if (needmask) {
                        int key = kbase + n * 16 + fr;
                        int qg = q0w + m * 16 + (g << 2) + r;
                        if (key > qg) sv = -1e30f;
                    }
                    s[m][n][r] = sv;
                }

        // ---- online softmax ----
        float alpha_[2][4];
#pragma unroll
        for (int m = 0; m < 2; m++)
#pragma unroll
            for (int r = 0; r < 4; r++) {
                float v = fmaxf(fmaxf(s[m][0][r], s[m][1][r]), fmaxf(s[m][2][r], s[m][3][r]));
                v = fmaxf(v, __shfl_xor(v, 1, 64));
                v = fmaxf(v, __shfl_xor(v, 2, 64));
                v = fmaxf(v, __shfl_xor(v, 4, 64));
                v = fmaxf(v, __shfl_xor(v, 8, 64));
                float mn = fmaxf(m_i[m][r], v);
                alpha_[m][r] = __expf(m_i[m][r] - mn);
                m_i[m][r] = mn;
            }
#pragma unroll
        for (int m = 0; m < 2; m++)
#pragma unroll
            for (int r = 0; r < 4; r++) {
                float rs = 0.f;
#pragma unroll
                for (int n = 0; n < 4; n++) {
                    float p = __expf(s[m][n][r] - m_i[m][r]);
                    s[m][n][r] = p;
                    rs += p;
                }
                rs += __shfl_xor(rs, 1, 64);
                rs += __shfl_xor(rs, 2, 64);
                rs += __shfl_xor(rs, 4, 64);
                rs += __shfl_xor(rs, 8, 64);
                l_i[m][r] = l_i[m][r] * alpha_[m][r] + rs;
            }

        // ---- P -> per-wave LDS (C/D layout -> A-frag layout) ----
#pragma unroll
        for (int m = 0; m < 2; m++)
#pragma unroll
            for (int n = 0; n < 4; n++)
#pragma unroll
                for (int r = 0; r < 4; r++)
                    Plds[w][m * 16 + (g << 2) + r][n * 16 + fr] = bf16_rne(s[m][n][r]);

        // ---- rescale O ----
#pragma unroll
        for (int m = 0; m < 2; m++)
#pragma unroll
            for (int n = 0; n < 8; n++)
#pragma unroll
                for (int r = 0; r < 4; r++) o[m][n][r] *= alpha_[m][r];

        // ---- PV ----
#pragma unroll
        for (int ks = 0; ks < 2; ks++) {
            frag_t pa[2];
#pragma unroll
            for (int m = 0; m < 2; m++)
                pa[m] = *(const frag_t*)&Plds[w][m * 16 + fr][ks * 32 + g * 8];
#pragma unroll
            for (int n = 0; n < 8; n++) {
                frag_t vb = *(const frag_t*)&Vt[n * 16 + fr][((4 * ks + g) ^ ((n >> 1) & 3)) << 3];
                o[0][n] = __builtin_amdgcn_mfma_f32_16x16x32_bf16(pa[0], vb, o[0][n], 0, 0, 0);
                o[1][n] = __builtin_amdgcn_mfma_f32_16x16x32_bf16(pa[1], vb, o[1][n], 0, 0, 0);
            }
        }
    }

    // ---- epilogue: write attnb as GEMM2 A-panels, hi plane only ----
#pragma unroll
    for (int m = 0; m < 2; m++)
#pragma unroll
        for (int r = 0; r < 4; r++) {
            float inv = 1.f / l_i[m][r];
            int rowg = b * 2048 + q0w + m * 16 + (g << 2) + r;
            int R = rowg & 127;
            size_t pbase = ((size_t)(rowg >> 7) * 64) << 12;  // kpan=64 for K=2048
            int rsw = (R >> 1) & 3;
#pragma unroll
            for (int n = 0; n < 8; n++) {
                int col = h * 128 + n * 16 + fr;  // k-dim of GEMM2
                int kt2 = col >> 5, kk = col & 31;
                int slot = ((kk >> 3) & 3) ^ rsw;
                size_t idx = pbase + ((size_t)kt2 << 12) + R * 32 + slot * 8 + (kk & 7);
                ATh[idx] = bf16_rne(o[m][n][r] * inv);
            }
        }
}

extern "C" void kernel_launch(void* const* d_in, const int* in_sizes, int n_in,
                              void* d_out, int out_size, void* d_ws, size_t ws_size,
                              hipStream_t stream) {
    const float* x = nullptr;
    const float* Wqkv = nullptr;
    const float* Wo = nullptr;
    const float* freqs = nullptr;
    for (int i = 0; i < n_in; i++) {
        switch (in_sizes[i]) {
            case 8388608:  x = (const float*)d_in[i]; break;
            case 12582912: Wqkv = (const float*)d_in[i]; break;
            case 4194304:  Wo = (const float*)d_in[i]; break;
            case 262144:   freqs = (const float*)d_in[i]; break;
        }
    }
    if (!x) x = (const float*)d_in[0];
    if (!Wqkv) Wqkv = (const float*)d_in[1];
    if (!Wo) Wo = (const float*)d_in[2];
    if (!freqs) freqs = (const float*)d_in[3];

    float* out = (float*)d_out;
    char* ws = (char*)d_ws;

    // Workspace schedule (peak 128 MiB, proven footprint):
    //  [0, 48Mi)       qkv_h bf16 plane [4096][6144]   (GEMM1 -> rope -> attn)
    //  [48Mi, 96Mi)    qkv_l bf16 plane
    //  [96Mi, 120Mi)   WqkvT hi/lo panels (per GEMM1 half; dead after GEMM1)
    //  [96Mi, 112Mi)   attnb hi A-panels (written by attn)
    //  [0, 16Mi)       WoT hi/lo panels (written after attn; qkv dead)
    u16* qkv_h = (u16*)ws;
    u16* qkv_l = (u16*)(ws + 50331648);
    u16* WTh = (u16*)(ws + 100663296);
    u16* WTl = (u16*)(ws + 100663296 + 12582912);
    u16* ATh = (u16*)(ws + 100663296);
    u16* WoTh = (u16*)ws;
    u16* WoTl = (u16*)(ws + 8388608);

    // GEMM1 in two 3072-col halves: qkv planes = split(x_hi @ Wqkv)
    transpose_split<<<64 * 96, 256, 0, stream>>>(Wqkv, WTh, WTl, 2048, 6144, 0, 3072);
    gemm_core<0, 1><<<768, 256, 0, stream>>>(x, nullptr, WTh, WTl,
                                             nullptr, qkv_h, qkv_l, 2048, 6144, 0, 3072);
    transpose_split<<<64 * 96, 256, 0, stream>>>(Wqkv, WTh, WTl, 2048, 6144, 3072, 3072);
    gemm_core<0, 1><<<768, 256, 0, stream>>>(x, nullptr, WTh, WTl,
                                             nullptr, qkv_h, qkv_l, 2048, 6144, 3072, 3072);
    // RoPE on split planes
    rope_planes<<<8192, 256, 0, stream>>>(qkv_h, qkv_l, freqs);
    // causal SDPA (MFMA flash) -> attnb hi panels
    attn_mfma<<<512, 256, 0, stream>>>(qkv_h, qkv_l, ATh);
    // out = attn_hi @ Wo (hi+lo)
    transpose_split<<<64 * 64, 256, 0, stream>>>(Wo, WoTh, WoTl, 2048, 2048, 0, 2048);
    gemm_core<1, 0><<<512, 256, 0, stream>>>(nullptr, ATh, WoTh, WoTl,
                                             out, nullptr, nullptr, 2048, 2048, 0, 2048);
}

// Round 7
// 606.678 us; speedup vs baseline: 1.5019x; 1.1551x over previous
//
#include <hip/hip_runtime.h>
#include <stdint.h>
#include <type_traits>

typedef unsigned short u16;
typedef __attribute__((ext_vector_type(8))) short short8_t;
typedef __attribute__((ext_vector_type(8))) __bf16 bf16x8_t;
typedef __attribute__((ext_vector_type(8))) unsigned short ushort8_t;
typedef __attribute__((ext_vector_type(4))) float f32x4;

// ROCm builds differ on the gfx950 bf16 MFMA builtin operand type
// (v8i16 vs v8bf16). Probe at compile time; bits are identical either way.
template <class T, class = void>
struct mfma_takes : std::false_type {};
template <class T>
struct mfma_takes<T, std::void_t<decltype(__builtin_amdgcn_mfma_f32_16x16x32_bf16(
                         std::declval<T>(), std::declval<T>(), std::declval<f32x4>(), 0, 0, 0))>>
    : std::true_type {};
using frag_t = std::conditional_t<mfma_takes<short8_t>::value, short8_t, bf16x8_t>;

__device__ __forceinline__ u16 bf16_rne(float f) {
    uint32_t u = __builtin_bit_cast(uint32_t, f);
    return (u16)((u + 0x7fffu + ((u >> 16) & 1u)) >> 16);
}
__device__ __forceinline__ float bf16_hi_f(u16 h) {
    return __builtin_bit_cast(float, (uint32_t)h << 16);
}

// ---- async global->LDS, 16B per lane. LDS dest = wave-uniform base + lane*16.
__device__ __forceinline__ void gl_lds16(const void* g, void* lds_base, int lane) {
#if defined(__has_builtin) && __has_builtin(__builtin_amdgcn_global_load_lds)
    typedef const __attribute__((address_space(1))) void* gp_t;
    typedef __attribute__((address_space(3))) void* lp_t;
    __builtin_amdgcn_global_load_lds((gp_t)g, (lp_t)lds_base, 16, 0, 0);
#else
    *(ushort8_t*)((char*)lds_base + lane * 16) = *(const ushort8_t*)g;
#endif
}

// ---------- transpose + split fp32 W[K][Nfull] cols [c0,c0+Ncols) ->
// bf16 hi/lo PANEL-TILED: panel p = (nloc>>7)*(K/32) + (k>>5), 8KB each,
// in-panel u16 idx = R*32 + slot*8 + (k&7), slot = ((k>>3)&3) ^ ((R>>1)&3).
// (verified rounds 3/5: absmax preserved)
__global__ __launch_bounds__(256) void transpose_split(const float* __restrict__ W,
                                                       u16* __restrict__ Th,
                                                       u16* __restrict__ Tl,
                                                       int K, int Nfull, int c0, int Ncols) {
    __shared__ float tile[32][33];
    const int nb = Ncols >> 5;
    const int bk = blockIdx.x / nb;
    const int bn = blockIdx.x % nb;
    const int tx = threadIdx.x & 31;
    const int ty = threadIdx.x >> 5;
    const int kpan = K >> 5;
#pragma unroll
    for (int i = 0; i < 4; i++) {
        int r = (i << 3) + ty;
        tile[r][tx] = W[(size_t)((bk << 5) + r) * Nfull + c0 + (bn << 5) + tx];
    }
    __syncthreads();
#pragma unroll
    for (int i = 0; i < 4; i++) {
        int r = (i << 3) + ty;
        float v = tile[tx][r];
        u16 h = bf16_rne(v);
        u16 l = bf16_rne(v - bf16_hi_f(h));
        int nloc = (bn << 5) + r;
        int R = nloc & 127;
        int slot = ((tx >> 3) & 3) ^ ((R >> 1) & 3);
        size_t o = (((size_t)(nloc >> 7) * kpan + bk) << 12) + R * 32 + (slot << 3) + (tx & 7);
        Th[o] = h;
        Tl[o] = l;
    }
}

// ---------- 2-term split-bf16 MFMA GEMM core (verified round 6) ----------
// C = A_hi @ (B_hi + B_lo)  — dropped a_lo*b term ~1.4e-3 rms (K=2048).
// AMODE 0: A fp32, staged hi-only conversion. AMODE 1: A pre-split hi panel.
// B: pre-split hi+lo panels via global_load_lds. CMODE 0: fp32 C. CMODE 1: planes.
// 128x128 tile, BK=32, 4 waves of 64x64. XCD-swizzled blockIdx (grid%8==0).
template <int AMODE, int CMODE>
__global__ __launch_bounds__(256) void gemm_core(const float* __restrict__ A32,
                                                 const u16* __restrict__ APh,
                                                 const u16* __restrict__ BPh,
                                                 const u16* __restrict__ BPl,
                                                 float* __restrict__ C32,
                                                 u16* __restrict__ Ch, u16* __restrict__ Cl,
                                                 int K, int Nfull, int n0, int Nloc) {
    constexpr int SMEM = (AMODE == 0) ? (10240 + 16384) : 24576;
    __shared__ alignas(16) char smem[SMEM];
    u16* Ah;   // AMODE0: [128][40] padded, hi only
    u16* Ahs;  // AMODE1: 8KB swizzled panel, hi only
    u16* Bhs; u16* Bls;
    if constexpr (AMODE == 0) {
        Ah = (u16*)smem;
        Bhs = (u16*)(smem + 10240); Bls = (u16*)(smem + 18432);
        Ahs = nullptr;
    } else {
        Ahs = (u16*)smem;
        Bhs = (u16*)(smem + 8192); Bls = (u16*)(smem + 16384);
        Ah = nullptr;
    }

    const int t = threadIdx.x;
    // T1: XCD-aware swizzle — contiguous grid chunk per XCD for L2 locality.
    const int nwg = gridDim.x;
    const int raw = blockIdx.x;
    const int bid = (raw & 7) * (nwg >> 3) + (raw >> 3);
    const int nb = Nloc >> 7;
    const int bm = bid / nb;
    const int bn = bid % nb;
    const int m0 = bm << 7;
    const int nl0 = bn << 7;

    const int lane = t & 63;
    const int w = t >> 6;
    const int fr = lane & 15;
    const int g = lane >> 4;
    const int wm = (w >> 1) << 6;
    const int wn = (w & 1) << 6;

    f32x4 acc[4][4];
#pragma unroll
    for (int m = 0; m < 4; m++)
#pragma unroll
        for (int n = 0; n < 4; n++) acc[m][n] = (f32x4)(0.0f);

    const int kpan = K >> 5;
    for (int kt = 0; kt < kpan; kt++) {
        if (kt) __syncthreads();
        // ---- stage A (hi only) ----
        if constexpr (AMODE == 0) {
            const int sr = t >> 3, sc = (t & 7) << 2;
#pragma unroll
            for (int rg = 0; rg < 4; rg++) {
                int row = (rg << 5) + sr;
                float4 v = *(const float4*)(A32 + (size_t)(m0 + row) * K + (kt << 5) + sc);
                *(ushort4*)&Ah[row * 40 + sc] =
                    make_ushort4(bf16_rne(v.x), bf16_rne(v.y), bf16_rne(v.z), bf16_rne(v.w));
            }
        } else {
            const u16* ph = APh + ((size_t)(bm * kpan + kt) << 12);
#pragma unroll
            for (int c = 0; c < 2; c++) {
                int o16 = (w << 10) + (c << 9);
                gl_lds16(ph + o16 + (lane << 3), (char*)Ahs + (o16 << 1), lane);
            }
        }
        // ---- stage B hi+lo (pre-split panels, linear copy) ----
        {
            const u16* ph = BPh + ((size_t)(bn * kpan + kt) << 12);
            const u16* pl = BPl + ((size_t)(bn * kpan + kt) << 12);
#pragma unroll
            for (int c = 0; c < 2; c++) {
                int o16 = (w << 10) + (c << 9);
                gl_lds16(ph + o16 + (lane << 3), (char*)Bhs + (o16 << 1), lane);
                gl_lds16(pl + o16 + (lane << 3), (char*)Bls + (o16 << 1), lane);
            }
        }
        __syncthreads();

        frag_t ah[4], bh[4], bl[4];
#pragma unroll
        for (int i = 0; i < 4; i++) {
            int Ra = wm + (i << 4) + fr;
            if constexpr (AMODE == 0) {
                ah[i] = *(const frag_t*)(Ah + Ra * 40 + (g << 3));
            } else {
                int sa = (g ^ ((Ra >> 1) & 3)) << 3;
                ah[i] = *(const frag_t*)(Ahs + Ra * 32 + sa);
            }
            int Rb = wn + (i << 4) + fr;
            int sb = (g ^ ((Rb >> 1) & 3)) << 3;
            bh[i] = *(const frag_t*)(Bhs + Rb * 32 + sb);
            bl[i] = *(const frag_t*)(Bls + Rb * 32 + sb);
        }
#pragma unroll
        for (int m = 0; m < 4; m++)
#pragma unroll
            for (int n = 0; n < 4; n++) {
                acc[m][n] = __builtin_amdgcn_mfma_f32_16x16x32_bf16(ah[m], bh[n], acc[m][n], 0, 0, 0);
                acc[m][n] = __builtin_amdgcn_mfma_f32_16x16x32_bf16(ah[m], bl[n], acc[m][n], 0, 0, 0);
            }
    }

    // epilogue: C/D layout col=lane&15, row=(lane>>4)*4+reg (m89-verified)
#pragma unroll
    for (int m = 0; m < 4; m++) {
        int r0 = m0 + wm + (m << 4) + (g << 2);
#pragma unroll
        for (int n = 0; n < 4; n++) {
            int cc = n0 + nl0 + wn + (n << 4) + fr;
#pragma unroll
            for (int r = 0; r < 4; r++) {
                if constexpr (CMODE == 0) {
                    C32[(size_t)(r0 + r) * Nfull + cc] = acc[m][n][r];
                } else {
                    float v = acc[m][n][r];
                    u16 hh = bf16_rne(v);
                    Ch[(size_t)(r0 + r) * Nfull + cc] = hh;
                    Cl[(size_t)(r0 + r) * Nfull + cc] = bf16_rne(v - bf16_hi_f(hh));
                }
            }
        }
    }
}

// ---------- RoPE on split planes, 4 pairs/thread (verified round 5) ----------
__global__ __launch_bounds__(256) void rope_planes(u16* __restrict__ qh, u16* __restrict__ ql,
                                                   const float* __restrict__ freqs) {
    int idx = blockIdx.x * 256 + threadIdx.x;
    int row = idx >> 9;
    int gix = idx & 511;
    int part = gix >> 8;
    int rem = gix & 255;
    int h = rem >> 4;
    int d2g = (rem & 15) << 2;
    int s = row & 2047;
    size_t base = (size_t)row * 6144 + part * 2048 + h * 128 + (d2g << 1);
    ushort8_t vh = *(const ushort8_t*)(qh + base);
    ushort8_t vl = *(const ushort8_t*)(ql + base);
    ushort8_t oh, ol;
#pragma unroll
    for (int j = 0; j < 4; j++) {
        float c = freqs[((s << 6) + d2g + j) * 2 + 0];
        float sn = freqs[((s << 6) + d2g + j) * 2 + 1];
        float x0 = bf16_hi_f(vh[2 * j]) + bf16_hi_f(vl[2 * j]);
        float x1 = bf16_hi_f(vh[2 * j + 1]) + bf16_hi_f(vl[2 * j + 1]);
        float y0 = x0 * c - x1 * sn;
        float y1 = x1 * c + x0 * sn;
        u16 h0 = bf16_rne(y0), h1 = bf16_rne(y1);
        oh[2 * j] = h0;     ol[2 * j] = bf16_rne(y0 - bf16_hi_f(h0));
        oh[2 * j + 1] = h1; ol[2 * j + 1] = bf16_rne(y1 - bf16_hi_f(h1));
    }
    *(ushort8_t*)(qh + base) = oh;
    *(ushort8_t*)(ql + base) = ol;
}

// ---------- MFMA causal flash attention, 2-term QK^T ----------
// QK^T = (qh+ql) . kh  (dropped q.kl term ~1e-3 on scores). Kl array deleted:
// LDS 54272 B -> 3 blocks/CU fit BY HARDWARE at 128 VGPR.
// FIX vs round 6: __launch_bounds__(256,2) — the (256,3) cap forced VGPR
// 128->84 and SPILLED the O-accumulators/Q-frags to scratch (FETCH 42->116MB,
// WRITE 35->70MB, MfmaUtil halved). Live state needs ~128 VGPR; at 128 the
// HW can still co-schedule 3 blocks/CU (LDS-limited), no cap needed.
__global__ __launch_bounds__(256, 2) void attn_mfma(const u16* __restrict__ qkv_h,
                                                    const u16* __restrict__ qkv_l,
                                                    u16* __restrict__ ATh) {
    __shared__ alignas(16) u16 Kh[64][136];
    __shared__ alignas(16) u16 Vt[128][72];
    __shared__ alignas(16) u16 Plds[4][32][72];

    const int t = threadIdx.x;
    const int lane = t & 63;
    const int w = t >> 6;
    const int g = lane >> 4;
    const int fr = lane & 15;

    const int bid = blockIdx.x;
    const int bh = bid & 31;
    const int x = bid >> 5;
    const int qb = (x & 1) ? (15 - (x >> 1)) : (x >> 1);
    const int b = bh >> 4;
    const int h = bh & 15;
    const int q0w = (qb << 7) + (w << 5);
    const float scale = 0.08838834764831845f;  // 1/sqrt(128)

    // ---- Q fragments: direct pre-split loads ----
    frag_t qh[2][4], ql[2][4];
#pragma unroll
    for (int m = 0; m < 2; m++) {
        size_t rb = (size_t)(b * 2048 + q0w + m * 16 + fr) * 6144 + h * 128 + (g << 3);
#pragma unroll
        for (int ks = 0; ks < 4; ks++) {
            qh[m][ks] = *(const frag_t*)(qkv_h + rb + ks * 32);
            ql[m][ks] = *(const frag_t*)(qkv_l + rb + ks * 32);
        }
    }

    f32x4 o[2][8];
#pragma unroll
    for (int m = 0; m < 2; m++)
#pragma unroll
        for (int n = 0; n < 8; n++) o[m][n] = (f32x4)(0.0f);
    float m_i[2][4], l_i[2][4];
#pragma unroll
    for (int m = 0; m < 2; m++)
#pragma unroll
        for (int r = 0; r < 4; r++) { m_i[m][r] = -1e30f; l_i[m][r] = 0.f; }

    const int kr = t >> 3;        // 0..31
    const int kc = (t & 7) << 4;  // u16 col 0..112, 16 u16 per thread
    const int vr = t >> 2;        // 0..63
    const int vc = (t & 3) << 5;  // u16 col 0..96

    const int ntile = 2 * qb + 2;
    for (int kt = 0; kt < ntile; kt++) {
        const int kbase = kt << 6;
        if (kt) __syncthreads();

        // ---- stage K hi plane only (16 u16/thread/pass) ----
        {
            size_t ksrc = (size_t)(b * 2048 + kbase) * 6144 + 2048 + h * 128 + kc;
#pragma unroll
            for (int p = 0; p < 2; p++) {
                int row = kr + (p << 5);
                size_t oo = ksrc + (size_t)row * 6144;
                *(ushort8_t*)&Kh[row][kc] = *(const ushort8_t*)(qkv_h + oo);
                *(ushort8_t*)&Kh[row][kc + 8] = *(const ushort8_t*)(qkv_h + oo + 8);
            }
        }
        // ---- stage V transposed (hi plane), 16B-block swizzle ----
        {
            size_t vsrc = (size_t)(b * 2048 + kbase + vr) * 6144 + 4096 + h * 128 + vc;
#pragma unroll
            for (int i = 0; i < 4; i++) {
                ushort8_t v = *(const ushort8_t*)(qkv_h + vsrc + (i << 3));
                int d0 = vc + (i << 3);
#pragma unroll
                for (int j = 0; j < 8; j++) {
                    int d = d0 + j;
                    int sw = (vr & 7) + ((((vr >> 3) ^ ((d >> 5) & 3))) << 3);
                    Vt[d][sw] = v[j];
                }
            }
        }
        __syncthreads();

        if (kbase > q0w + 31) continue;  // fully masked for this wave

        // ---- QK^T: 2-term split (qh + ql) . kh ----
        f32x4 s[2][4];
#pragma unroll
        for (int m = 0; m < 2; m++)
#pragma unroll
            for (int n = 0; n < 4; n++) s[m][n] = (f32x4)(0.0f);
#pragma unroll
        for (int ks = 0; ks < 4; ks++) {
            frag_t kh[4];
#pragma unroll
            for (int n = 0; n < 4; n++)
                kh[n] = *(const frag_t*)&Kh[n * 16 + fr][ks * 32 + g * 8];
#pragma unroll
            for (int m = 0; m < 2; m++)
#pragma unroll
                for (int n = 0; n < 4; n++) {
                    s[m][n] = __builtin_amdgcn_mfma_f32_16x16x32_bf16(qh[m][ks], kh[n], s[m][n], 0, 0, 0);
                    s[m][n] = __builtin_amdgcn_mfma_f32_16x16x32_bf16(ql[m][ks], kh[n], s[m][n], 0, 0, 0);
                }
        }

        // ---- scale + causal mask ----
        const bool needmask = (kbase + 63 > q0w);
#pragma unroll
        for (int m = 0; m < 2; m++)
#pragma unroll
            for (int n = 0; n < 4; n++)
#pragma unroll
                for (int r = 0; r < 4; r++) {
                    float sv = s[m][n][r] * scale;
                    if (needmask) {
                        int key = kbase + n * 16 + fr;
                        int qg = q0w + m * 16 + (g << 2) + r;
                        if (key > qg) sv = -1e30f;
                    }
                    s[m][n][r] = sv;
                }

        // ---- online softmax ----
        float alpha_[2][4];
#pragma unroll
        for (int m = 0; m < 2; m++)
#pragma unroll
            for (int r = 0; r < 4; r++) {
                float v = fmaxf(fmaxf(s[m][0][r], s[m][1][r]), fmaxf(s[m][2][r], s[m][3][r]));
                v = fmaxf(v, __shfl_xor(v, 1, 64));
                v = fmaxf(v, __shfl_xor(v, 2, 64));
                v = fmaxf(v, __shfl_xor(v, 4, 64));
                v = fmaxf(v, __shfl_xor(v, 8, 64));
                float mn = fmaxf(m_i[m][r], v);
                alpha_[m][r] = __expf(m_i[m][r] - mn);
                m_i[m][r] = mn;
            }
#pragma unroll
        for (int m = 0; m < 2; m++)
#pragma unroll
            for (int r = 0; r < 4; r++) {
                float rs = 0.f;
#pragma unroll
                for (int n = 0; n < 4; n++) {
                    float p = __expf(s[m][n][r] - m_i[m][r]);
                    s[m][n][r] = p;
                    rs += p;
                }
                rs += __shfl_xor(rs, 1, 64);
                rs += __shfl_xor(rs, 2, 64);
                rs += __shfl_xor(rs, 4, 64);
                rs += __shfl_xor(rs, 8, 64);
                l_i[m][r] = l_i[m][r] * alpha_[m][r] + rs;
            }

        // ---- P -> per-wave LDS (C/D layout -> A-frag layout) ----
#pragma unroll
        for (int m = 0; m < 2; m++)
#pragma unroll
            for (int n = 0; n < 4; n++)
#pragma unroll
                for (int r = 0; r < 4; r++)
                    Plds[w][m * 16 + (g << 2) + r][n * 16 + fr] = bf16_rne(s[m][n][r]);

        // ---- rescale O ----
#pragma unroll
        for (int m = 0; m < 2; m++)
#pragma unroll
            for (int n = 0; n < 8; n++)
#pragma unroll
                for (int r = 0; r < 4; r++) o[m][n][r] *= alpha_[m][r];

        // ---- PV ----
#pragma unroll
        for (int ks = 0; ks < 2; ks++) {
            frag_t pa[2];
#pragma unroll
            for (int m = 0; m < 2; m++)
                pa[m] = *(const frag_t*)&Plds[w][m * 16 + fr][ks * 32 + g * 8];
#pragma unroll
            for (int n = 0; n < 8; n++) {
                frag_t vb = *(const frag_t*)&Vt[n * 16 + fr][((4 * ks + g) ^ ((n >> 1) & 3)) << 3];
                o[0][n] = __builtin_amdgcn_mfma_f32_16x16x32_bf16(pa[0], vb, o[0][n], 0, 0, 0);
                o[1][n] = __builtin_amdgcn_mfma_f32_16x16x32_bf16(pa[1], vb, o[1][n], 0, 0, 0);
            }
        }
    }

    // ---- epilogue: write attnb as GEMM2 A-panels, hi plane only ----
#pragma unroll
    for (int m = 0; m < 2; m++)
#pragma unroll
        for (int r = 0; r < 4; r++) {
            float inv = 1.f / l_i[m][r];
            int rowg = b * 2048 + q0w + m * 16 + (g << 2) + r;
            int R = rowg & 127;
            size_t pbase = ((size_t)(rowg >> 7) * 64) << 12;  // kpan=64 for K=2048
            int rsw = (R >> 1) & 3;
#pragma unroll
            for (int n = 0; n < 8; n++) {
                int col = h * 128 + n * 16 + fr;  // k-dim of GEMM2
                int kt2 = col >> 5, kk = col & 31;
                int slot = ((kk >> 3) & 3) ^ rsw;
                size_t idx = pbase + ((size_t)kt2 << 12) + R * 32 + slot * 8 + (kk & 7);
                ATh[idx] = bf16_rne(o[m][n][r] * inv);
            }
        }
}

extern "C" void kernel_launch(void* const* d_in, const int* in_sizes, int n_in,
                              void* d_out, int out_size, void* d_ws, size_t ws_size,
                              hipStream_t stream) {
    const float* x = nullptr;
    const float* Wqkv = nullptr;
    const float* Wo = nullptr;
    const float* freqs = nullptr;
    for (int i = 0; i < n_in; i++) {
        switch (in_sizes[i]) {
            case 8388608:  x = (const float*)d_in[i]; break;
            case 12582912: Wqkv = (const float*)d_in[i]; break;
            case 4194304:  Wo = (const float*)d_in[i]; break;
            case 262144:   freqs = (const float*)d_in[i]; break;
        }
    }
    if (!x) x = (const float*)d_in[0];
    if (!Wqkv) Wqkv = (const float*)d_in[1];
    if (!Wo) Wo = (const float*)d_in[2];
    if (!freqs) freqs = (const float*)d_in[3];

    float* out = (float*)d_out;
    char* ws = (char*)d_ws;

    // Workspace schedule (peak 128 MiB, proven footprint):
    //  [0, 48Mi)       qkv_h bf16 plane [4096][6144]   (GEMM1 -> rope -> attn)
    //  [48Mi, 96Mi)    qkv_l bf16 plane
    //  [96Mi, 120Mi)   WqkvT hi/lo panels (per GEMM1 half; dead after GEMM1)
    //  [96Mi, 112Mi)   attnb hi A-panels (written by attn)
    //  [0, 16Mi)       WoT hi/lo panels (written after attn; qkv dead)
    u16* qkv_h = (u16*)ws;
    u16* qkv_l = (u16*)(ws + 50331648);
    u16* WTh = (u16*)(ws + 100663296);
    u16* WTl = (u16*)(ws + 100663296 + 12582912);
    u16* ATh = (u16*)(ws + 100663296);
    u16* WoTh = (u16*)ws;
    u16* WoTl = (u16*)(ws + 8388608);

    // GEMM1 in two 3072-col halves: qkv planes = split(x_hi @ Wqkv)
    transpose_split<<<64 * 96, 256, 0, stream>>>(Wqkv, WTh, WTl, 2048, 6144, 0, 3072);
    gemm_core<0, 1><<<768, 256, 0, stream>>>(x, nullptr, WTh, WTl,
                                             nullptr, qkv_h, qkv_l, 2048, 6144, 0, 3072);
    transpose_split<<<64 * 96, 256, 0, stream>>>(Wqkv, WTh, WTl, 2048, 6144, 3072, 3072);
    gemm_core<0, 1><<<768, 256, 0, stream>>>(x, nullptr, WTh, WTl,
                                             nullptr, qkv_h, qkv_l, 2048, 6144, 3072, 3072);
    // RoPE on split planes
    rope_planes<<<8192, 256, 0, stream>>>(qkv_h, qkv_l, freqs);
    // causal SDPA (MFMA flash) -> attnb hi panels
    attn_mfma<<<512, 256, 0, stream>>>(qkv_h, qkv_l, ATh);
    // out = attn_hi @ Wo (hi+lo)
    transpose_split<<<64 * 64, 256, 0, stream>>>(Wo, WoTh, WoTl, 2048, 2048, 0, 2048);
    gemm_core<1, 0><<<512, 256, 0, stream>>>(nullptr, ATh, WoTh, WoTl,
                                             out, nullptr, nullptr, 2048, 2048, 0, 2048);
}

// Round 8
// 595.740 us; speedup vs baseline: 1.5294x; 1.0184x over previous
//
#include <hip/hip_runtime.h>
#include <stdint.h>
#include <type_traits>

typedef unsigned short u16;
typedef __attribute__((ext_vector_type(8))) short short8_t;
typedef __attribute__((ext_vector_type(8))) __bf16 bf16x8_t;
typedef __attribute__((ext_vector_type(8))) unsigned short ushort8_t;
typedef __attribute__((ext_vector_type(4))) float f32x4;

// ROCm builds differ on the gfx950 bf16 MFMA builtin operand type
// (v8i16 vs v8bf16). Probe at compile time; bits are identical either way.
template <class T, class = void>
struct mfma_takes : std::false_type {};
template <class T>
struct mfma_takes<T, std::void_t<decltype(__builtin_amdgcn_mfma_f32_16x16x32_bf16(
                         std::declval<T>(), std::declval<T>(), std::declval<f32x4>(), 0, 0, 0))>>
    : std::true_type {};
using frag_t = std::conditional_t<mfma_takes<short8_t>::value, short8_t, bf16x8_t>;

__device__ __forceinline__ u16 bf16_rne(float f) {
    uint32_t u = __builtin_bit_cast(uint32_t, f);
    return (u16)((u + 0x7fffu + ((u >> 16) & 1u)) >> 16);
}
__device__ __forceinline__ float bf16_hi_f(u16 h) {
    return __builtin_bit_cast(float, (uint32_t)h << 16);
}

// ---- async global->LDS, 16B per lane. LDS dest = wave-uniform base + lane*16.
__device__ __forceinline__ void gl_lds16(const void* g, void* lds_base, int lane) {
#if defined(__has_builtin) && __has_builtin(__builtin_amdgcn_global_load_lds)
    typedef const __attribute__((address_space(1))) void* gp_t;
    typedef __attribute__((address_space(3))) void* lp_t;
    __builtin_amdgcn_global_load_lds((gp_t)g, (lp_t)lds_base, 16, 0, 0);
#else
    *(ushort8_t*)((char*)lds_base + lane * 16) = *(const ushort8_t*)g;
#endif
}

// ---------- transpose + split fp32 W[K][Nfull] cols [c0,c0+Ncols) ->
// bf16 hi/lo PANEL-TILED: panel p = (nloc>>7)*(K/32) + (k>>5), 8KB each,
// in-panel u16 idx = R*32 + slot*8 + (k&7), slot = ((k>>3)&3) ^ ((R>>1)&3).
// (verified rounds 3/5/7: absmax preserved)
__global__ __launch_bounds__(256) void transpose_split(const float* __restrict__ W,
                                                       u16* __restrict__ Th,
                                                       u16* __restrict__ Tl,
                                                       int K, int Nfull, int c0, int Ncols) {
    __shared__ float tile[32][33];
    const int nb = Ncols >> 5;
    const int bk = blockIdx.x / nb;
    const int bn = blockIdx.x % nb;
    const int tx = threadIdx.x & 31;
    const int ty = threadIdx.x >> 5;
    const int kpan = K >> 5;
#pragma unroll
    for (int i = 0; i < 4; i++) {
        int r = (i << 3) + ty;
        tile[r][tx] = W[(size_t)((bk << 5) + r) * Nfull + c0 + (bn << 5) + tx];
    }
    __syncthreads();
#pragma unroll
    for (int i = 0; i < 4; i++) {
        int r = (i << 3) + ty;
        float v = tile[tx][r];
        u16 h = bf16_rne(v);
        u16 l = bf16_rne(v - bf16_hi_f(h));
        int nloc = (bn << 5) + r;
        int R = nloc & 127;
        int slot = ((tx >> 3) & 3) ^ ((R >> 1) & 3);
        size_t o = (((size_t)(nloc >> 7) * kpan + bk) << 12) + R * 32 + (slot << 3) + (tx & 7);
        Th[o] = h;
        Tl[o] = l;
    }
}

// ---------- convert fp32 X[4096][2048] -> hi-bf16 A-panels (once, not per-block)
// Same panel layout as transpose_split / attn epilogue. Values = bf16_rne(x):
// bit-identical to the previous in-loop staged conversion.
__global__ __launch_bounds__(256) void convert_x_panels(const float* __restrict__ X,
                                                        u16* __restrict__ XPh) {
    int r = blockIdx.x;   // row 0..4095
    int c = threadIdx.x;  // 8-k chunk 0..255
    const float* src = X + (size_t)r * 2048 + (c << 3);
    float4 v0 = *(const float4*)src;
    float4 v1 = *(const float4*)(src + 4);
    ushort8_t h;
    h[0] = bf16_rne(v0.x); h[1] = bf16_rne(v0.y); h[2] = bf16_rne(v0.z); h[3] = bf16_rne(v0.w);
    h[4] = bf16_rne(v1.x); h[5] = bf16_rne(v1.y); h[6] = bf16_rne(v1.z); h[7] = bf16_rne(v1.w);
    int R = r & 127;
    int slot = (c & 3) ^ ((R >> 1) & 3);
    size_t off = ((size_t)((r >> 7) * 64 + (c >> 2)) << 12) + R * 32 + slot * 8;
    *(ushort8_t*)(XPh + off) = h;
}

// ---------- 2-term split-bf16 MFMA GEMM, all-panel, 2-PHASE PIPELINE ----------
// C = A_hi @ (B_hi + B_lo). All operands pre-split swizzled panels staged via
// global_load_lds. Double-buffered LDS (2 x 24KB): stage(t+1) issued BEFORE
// ds_read/MFMA of tile t, ONE barrier per tile -> HBM latency hides under
// compute (minimum-2-phase schedule; T3 recipe).
// CMODE 0: fp32 C.  CMODE 1: hi/lo bf16 planes.
// 128x128 tile, BK=32, 4 waves of 64x64. XCD-swizzled blockIdx (grid%8==0).
template <int CMODE>
__global__ __launch_bounds__(256) void gemm_panels(const u16* __restrict__ APh,
                                                   const u16* __restrict__ BPh,
                                                   const u16* __restrict__ BPl,
                                                   float* __restrict__ C32,
                                                   u16* __restrict__ Ch, u16* __restrict__ Cl,
                                                   int K, int Nfull, int n0, int Nloc) {
    __shared__ alignas(16) u16 Ab[2][4096];
    __shared__ alignas(16) u16 Bh_[2][4096];
    __shared__ alignas(16) u16 Bl_[2][4096];

    const int t = threadIdx.x;
    // T1: XCD-aware swizzle — contiguous grid chunk per XCD for L2 locality.
    const int nwg = gridDim.x;
    const int raw = blockIdx.x;
    const int bid = (raw & 7) * (nwg >> 3) + (raw >> 3);
    const int nb = Nloc >> 7;
    const int bm = bid / nb;
    const int bn = bid % nb;
    const int m0 = bm << 7;
    const int nl0 = bn << 7;

    const int lane = t & 63;
    const int w = t >> 6;
    const int fr = lane & 15;
    const int g = lane >> 4;
    const int wm = (w >> 1) << 6;
    const int wn = (w & 1) << 6;

    const int kpan = K >> 5;

    auto stage = [&](int bu, int kt) {
        const u16* pa = APh + ((size_t)(bm * kpan + kt) << 12);
        const u16* ph = BPh + ((size_t)(bn * kpan + kt) << 12);
        const u16* pl = BPl + ((size_t)(bn * kpan + kt) << 12);
#pragma unroll
        for (int c = 0; c < 2; c++) {
            int o16 = (w << 10) + (c << 9);  // wave-uniform u16 offset
            gl_lds16(pa + o16 + (lane << 3), (char*)&Ab[bu][0] + (o16 << 1), lane);
            gl_lds16(ph + o16 + (lane << 3), (char*)&Bh_[bu][0] + (o16 << 1), lane);
            gl_lds16(pl + o16 + (lane << 3), (char*)&Bl_[bu][0] + (o16 << 1), lane);
        }
    };

    f32x4 acc[4][4];
#pragma unroll
    for (int m = 0; m < 4; m++)
#pragma unroll
        for (int n = 0; n < 4; n++) acc[m][n] = (f32x4)(0.0f);

    stage(0, 0);
    __syncthreads();  // drains vmcnt(0): buf0 ready
    int cur = 0;
    for (int kt = 0; kt < kpan; kt++) {
        if (kt + 1 < kpan) stage(cur ^ 1, kt + 1);  // issue next-tile loads FIRST

        frag_t ah[4], bh[4], bl[4];
#pragma unroll
        for (int i = 0; i < 4; i++) {
            int Ra = wm + (i << 4) + fr;
            int sa = (g ^ ((Ra >> 1) & 3)) << 3;
            ah[i] = *(const frag_t*)(&Ab[cur][0] + Ra * 32 + sa);
            int Rb = wn + (i << 4) + fr;
            int sb = (g ^ ((Rb >> 1) & 3)) << 3;
            bh[i] = *(const frag_t*)(&Bh_[cur][0] + Rb * 32 + sb);
            bl[i] = *(const frag_t*)(&Bl_[cur][0] + Rb * 32 + sb);
        }
#pragma unroll
        for (int m = 0; m < 4; m++)
#pragma unroll
            for (int n = 0; n < 4; n++) {
                acc[m][n] = __builtin_amdgcn_mfma_f32_16x16x32_bf16(ah[m], bh[n], acc[m][n], 0, 0, 0);
                acc[m][n] = __builtin_amdgcn_mfma_f32_16x16x32_bf16(ah[m], bl[n], acc[m][n], 0, 0, 0);
            }
        __syncthreads();  // next buf staged; reads of cur done
        cur ^= 1;
    }

    // epilogue: C/D layout col=lane&15, row=(lane>>4)*4+reg (m89-verified)
#pragma unroll
    for (int m = 0; m < 4; m++) {
        int r0 = m0 + wm + (m << 4) + (g << 2);
#pragma unroll
        for (int n = 0; n < 4; n++) {
            int cc = n0 + nl0 + wn + (n << 4) + fr;
#pragma unroll
            for (int r = 0; r < 4; r++) {
                if constexpr (CMODE == 0) {
                    C32[(size_t)(r0 + r) * Nfull + cc] = acc[m][n][r];
                } else {
                    float v = acc[m][n][r];
                    u16 hh = bf16_rne(v);
                    Ch[(size_t)(r0 + r) * Nfull + cc] = hh;
                    Cl[(size_t)(r0 + r) * Nfull + cc] = bf16_rne(v - bf16_hi_f(hh));
                }
            }
        }
    }
}

// ---------- RoPE on split planes, 4 pairs/thread (verified round 5) ----------
__global__ __launch_bounds__(256) void rope_planes(u16* __restrict__ qh, u16* __restrict__ ql,
                                                   const float* __restrict__ freqs) {
    int idx = blockIdx.x * 256 + threadIdx.x;
    int row = idx >> 9;
    int gix = idx & 511;
    int part = gix >> 8;
    int rem = gix & 255;
    int h = rem >> 4;
    int d2g = (rem & 15) << 2;
    int s = row & 2047;
    size_t base = (size_t)row * 6144 + part * 2048 + h * 128 + (d2g << 1);
    ushort8_t vh = *(const ushort8_t*)(qh + base);
    ushort8_t vl = *(const ushort8_t*)(ql + base);
    ushort8_t oh, ol;
#pragma unroll
    for (int j = 0; j < 4; j++) {
        float c = freqs[((s << 6) + d2g + j) * 2 + 0];
        float sn = freqs[((s << 6) + d2g + j) * 2 + 1];
        float x0 = bf16_hi_f(vh[2 * j]) + bf16_hi_f(vl[2 * j]);
        float x1 = bf16_hi_f(vh[2 * j + 1]) + bf16_hi_f(vl[2 * j + 1]);
        float y0 = x0 * c - x1 * sn;
        float y1 = x1 * c + x0 * sn;
        u16 h0 = bf16_rne(y0), h1 = bf16_rne(y1);
        oh[2 * j] = h0;     ol[2 * j] = bf16_rne(y0 - bf16_hi_f(h0));
        oh[2 * j + 1] = h1; ol[2 * j + 1] = bf16_rne(y1 - bf16_hi_f(h1));
    }
    *(ushort8_t*)(qh + base) = oh;
    *(ushort8_t*)(ql + base) = ol;
}

// ---------- MFMA causal flash attention, 2-term QK^T (verified round 7) ----------
// QK^T = (qh+ql) . kh. LDS 54272 B; __launch_bounds__(256,2): VGPR 124, no
// spill (round-6's (256,3) cap spilled accumulators — do not reinstate).
__global__ __launch_bounds__(256, 2) void attn_mfma(const u16* __restrict__ qkv_h,
                                                    const u16* __restrict__ qkv_l,
                                                    u16* __restrict__ ATh) {
    __shared__ alignas(16) u16 Kh[64][136];
    __shared__ alignas(16) u16 Vt[128][72];
    __shared__ alignas(16) u16 Plds[4][32][72];

    const int t = threadIdx.x;
    const int lane = t & 63;
    const int w = t >> 6;
    const int g = lane >> 4;
    const int fr = lane & 15;

    const int bid = blockIdx.x;
    const int bh = bid & 31;
    const int x = bid >> 5;
    const int qb = (x & 1) ? (15 - (x >> 1)) : (x >> 1);
    const int b = bh >> 4;
    const int h = bh & 15;
    const int q0w = (qb << 7) + (w << 5);
    const float scale = 0.08838834764831845f;  // 1/sqrt(128)

    frag_t qh[2][4], ql[2][4];
#pragma unroll
    for (int m = 0; m < 2; m++) {
        size_t rb = (size_t)(b * 2048 + q0w + m * 16 + fr) * 6144 + h * 128 + (g << 3);
#pragma unroll
        for (int ks = 0; ks < 4; ks++) {
            qh[m][ks] = *(const frag_t*)(qkv_h + rb + ks * 32);
            ql[m][ks] = *(const frag_t*)(qkv_l + rb + ks * 32);
        }
    }

    f32x4 o[2][8];
#pragma unroll
    for (int m = 0; m < 2; m++)
#pragma unroll
        for (int n = 0; n < 8; n++) o[m][n] = (f32x4)(0.0f);
    float m_i[2][4], l_i[2][4];
#pragma unroll
    for (int m = 0; m < 2; m++)
#pragma unroll
        for (int r = 0; r < 4; r++) { m_i[m][r] = -1e30f; l_i[m][r] = 0.f; }

    const int kr = t >> 3;        // 0..31
    const int kc = (t & 7) << 4;  // u16 col 0..112, 16 u16 per thread
    const int vr = t >> 2;        // 0..63
    const int vc = (t & 3) << 5;  // u16 col 0..96

    const int ntile = 2 * qb + 2;
    for (int kt = 0; kt < ntile; kt++) {
        const int kbase = kt << 6;
        if (kt) __syncthreads();

        {
            size_t ksrc = (size_t)(b * 2048 + kbase) * 6144 + 2048 + h * 128 + kc;
#pragma unroll
            for (int p = 0; p < 2; p++) {
                int row = kr + (p << 5);
                size_t oo = ksrc + (size_t)row * 6144;
                *(ushort8_t*)&Kh[row][kc] = *(const ushort8_t*)(qkv_h + oo);
                *(ushort8_t*)&Kh[row][kc + 8] = *(const ushort8_t*)(qkv_h + oo + 8);
            }
        }
        {
            size_t vsrc = (size_t)(b * 2048 + kbase + vr) * 6144 + 4096 + h * 128 + vc;
#pragma unroll
            for (int i = 0; i < 4; i++) {
                ushort8_t v = *(const ushort8_t*)(qkv_h + vsrc + (i << 3));
                int d0 = vc + (i << 3);
#pragma unroll
                for (int j = 0; j < 8; j++) {
                    int d = d0 + j;
                    int sw = (vr & 7) + ((((vr >> 3) ^ ((d >> 5) & 3))) << 3);
                    Vt[d][sw] = v[j];
                }
            }
        }
        __syncthreads();

        if (kbase > q0w + 31) continue;  // fully masked for this wave

        f32x4 s[2][4];
#pragma unroll
        for (int m = 0; m < 2; m++)
#pragma unroll
            for (int n = 0; n < 4; n++) s[m][n] = (f32x4)(0.0f);
#pragma unroll
        for (int ks = 0; ks < 4; ks++) {
            frag_t kh[4];
#pragma unroll
            for (int n = 0; n < 4; n++)
                kh[n] = *(const frag_t*)&Kh[n * 16 + fr][ks * 32 + g * 8];
#pragma unroll
            for (int m = 0; m < 2; m++)
#pragma unroll
                for (int n = 0; n < 4; n++) {
                    s[m][n] = __builtin_amdgcn_mfma_f32_16x16x32_bf16(qh[m][ks], kh[n], s[m][n], 0, 0, 0);
                    s[m][n] = __builtin_amdgcn_mfma_f32_16x16x32_bf16(ql[m][ks], kh[n], s[m][n], 0, 0, 0);
                }
        }

        const bool needmask = (kbase + 63 > q0w);
#pragma unroll
        for (int m = 0; m < 2; m++)
#pragma unroll
            for (int n = 0; n < 4; n++)
#pragma unroll
                for (int r = 0; r < 4; r++) {
                    float sv = s[m][n][r] * scale;
                    if (needmask) {
                        int key = kbase + n * 16 + fr;
                        int qg = q0w + m * 16 + (g << 2) + r;
                        if (key > qg) sv = -1e30f;
                    }
                    s[m][n][r] = sv;
                }

        float alpha_[2][4];
#pragma unroll
        for (int m = 0; m < 2; m++)
#pragma unroll
            for (int r = 0; r < 4; r++) {
                float v = fmaxf(fmaxf(s[m][0][r], s[m][1][r]), fmaxf(s[m][2][r], s[m][3][r]));
                v = fmaxf(v, __shfl_xor(v, 1, 64));
                v = fmaxf(v, __shfl_xor(v, 2, 64));
                v = fmaxf(v, __shfl_xor(v, 4, 64));
                v = fmaxf(v, __shfl_xor(v, 8, 64));
                float mn = fmaxf(m_i[m][r], v);
                alpha_[m][r] = __expf(m_i[m][r] - mn);
                m_i[m][r] = mn;
            }
#pragma unroll
        for (int m = 0; m < 2; m++)
#pragma unroll
            for (int r = 0; r < 4; r++) {
                float rs = 0.f;
#pragma unroll
                for (int n = 0; n < 4; n++) {
                    float p = __expf(s[m][n][r] - m_i[m][r]);
                    s[m][n][r] = p;
                    rs += p;
                }
                rs += __shfl_xor(rs, 1, 64);
                rs += __shfl_xor(rs, 2, 64);
                rs += __shfl_xor(rs, 4, 64);
                rs += __shfl_xor(rs, 8, 64);
                l_i[m][r] = l_i[m][r] * alpha_[m][r] + rs;
            }

#pragma unroll
        for (int m = 0; m < 2; m++)
#pragma unroll
            for (int n = 0; n < 4; n++)
#pragma unroll
                for (int r = 0; r < 4; r++)
                    Plds[w][m * 16 + (g << 2) + r][n * 16 + fr] = bf16_rne(s[m][n][r]);

#pragma unroll
        for (int m = 0; m < 2; m++)
#pragma unroll
            for (int n = 0; n < 8; n++)
#pragma unroll
                for (int r = 0; r < 4; r++) o[m][n][r] *= alpha_[m][r];

#pragma unroll
        for (int ks = 0; ks < 2; ks++) {
            frag_t pa[2];
#pragma unroll
            for (int m = 0; m < 2; m++)
                pa[m] = *(const frag_t*)&Plds[w][m * 16 + fr][ks * 32 + g * 8];
#pragma unroll
            for (int n = 0; n < 8; n++) {
                frag_t vb = *(const frag_t*)&Vt[n * 16 + fr][((4 * ks + g) ^ ((n >> 1) & 3)) << 3];
                o[0][n] = __builtin_amdgcn_mfma_f32_16x16x32_bf16(pa[0], vb, o[0][n], 0, 0, 0);
                o[1][n] = __builtin_amdgcn_mfma_f32_16x16x32_bf16(pa[1], vb, o[1][n], 0, 0, 0);
            }
        }
    }

    // epilogue: write attnb as GEMM2 A-panels, hi plane only
#pragma unroll
    for (int m = 0; m < 2; m++)
#pragma unroll
        for (int r = 0; r < 4; r++) {
            float inv = 1.f / l_i[m][r];
            int rowg = b * 2048 + q0w + m * 16 + (g << 2) + r;
            int R = rowg & 127;
            size_t pbase = ((size_t)(rowg >> 7) * 64) << 12;  // kpan=64 for K=2048
            int rsw = (R >> 1) & 3;
#pragma unroll
            for (int n = 0; n < 8; n++) {
                int col = h * 128 + n * 16 + fr;  // k-dim of GEMM2
                int kt2 = col >> 5, kk = col & 31;
                int slot = ((kk >> 3) & 3) ^ rsw;
                size_t idx = pbase + ((size_t)kt2 << 12) + R * 32 + slot * 8 + (kk & 7);
                ATh[idx] = bf16_rne(o[m][n][r] * inv);
            }
        }
}

extern "C" void kernel_launch(void* const* d_in, const int* in_sizes, int n_in,
                              void* d_out, int out_size, void* d_ws, size_t ws_size,
                              hipStream_t stream) {
    const float* x = nullptr;
    const float* Wqkv = nullptr;
    const float* Wo = nullptr;
    const float* freqs = nullptr;
    for (int i = 0; i < n_in; i++) {
        switch (in_sizes[i]) {
            case 8388608:  x = (const float*)d_in[i]; break;
            case 12582912: Wqkv = (const float*)d_in[i]; break;
            case 4194304:  Wo = (const float*)d_in[i]; break;
            case 262144:   freqs = (const float*)d_in[i]; break;
        }
    }
    if (!x) x = (const float*)d_in[0];
    if (!Wqkv) Wqkv = (const float*)d_in[1];
    if (!Wo) Wo = (const float*)d_in[2];
    if (!freqs) freqs = (const float*)d_in[3];

    float* out = (float*)d_out;
    char* ws = (char*)d_ws;

    // Workspace schedule (peak exactly 128 MiB):
    //  [0, 48Mi)          qkv_h bf16 plane [4096][6144]  (GEMM1 -> rope -> attn)
    //  [48Mi, 96Mi)       qkv_l bf16 plane
    //  [96Mi, 112Mi)      XPh: x hi-panels (live during GEMM1 thirds)
    //  [112Mi, 120Mi)     WTh third panel   (per GEMM1 third)
    //  [120Mi, 128Mi)     WTl third panel
    //  [96Mi, 112Mi)      ATh attn A-panels (after GEMM1; XPh dead)
    //  [0, 16Mi)          WoT hi/lo panels  (after attn; qkv dead)
    u16* qkv_h = (u16*)ws;
    u16* qkv_l = (u16*)(ws + 50331648);
    u16* XPh = (u16*)(ws + 100663296);
    u16* WTh = (u16*)(ws + 100663296 + 16777216);
    u16* WTl = (u16*)(ws + 100663296 + 16777216 + 8388608);
    u16* ATh = (u16*)(ws + 100663296);
    u16* WoTh = (u16*)ws;
    u16* WoTl = (u16*)(ws + 8388608);

    // x -> hi-bf16 panels (once)
    convert_x_panels<<<4096, 256, 0, stream>>>(x, XPh);
    // GEMM1 in three 2048-col thirds: qkv planes = split(x_hi @ Wqkv)
    for (int i = 0; i < 3; i++) {
        transpose_split<<<64 * 64, 256, 0, stream>>>(Wqkv, WTh, WTl, 2048, 6144, i * 2048, 2048);
        gemm_panels<1><<<512, 256, 0, stream>>>(XPh, WTh, WTl,
                                                nullptr, qkv_h, qkv_l, 2048, 6144, i * 2048, 2048);
    }
    // RoPE on split planes
    rope_planes<<<8192, 256, 0, stream>>>(qkv_h, qkv_l, freqs);
    // causal SDPA (MFMA flash) -> attnb hi panels
    attn_mfma<<<512, 256, 0, stream>>>(qkv_h, qkv_l, ATh);
    // out = attn_hi @ Wo (hi+lo)
    transpose_split<<<64 * 64, 256, 0, stream>>>(Wo, WoTh, WoTl, 2048, 2048, 0, 2048);
    gemm_panels<0><<<512, 256, 0, stream>>>(ATh, WoTh, WoTl,
                                            out, nullptr, nullptr, 2048, 2048, 0, 2048);
}